// Round 2
// baseline (542.416 us; speedup 1.0000x reference)
//
#include <hip/hip_runtime.h>
#include <hip/hip_bf16.h>

// Problem: B=16, T=S=2048, D=1024, H=24
#define B_ 16
#define T_ 2048
#define S_ 2048
#define D_ 1024
#define H_ 24
#define NROW_ (B_ * T_)     // 32768 rows for text; same count for encoded
#define QN_ (NROW_ * H_)    // 786432 floats per projection buffer
#define BS_ (B_ * S_)       // 32768

// ---------------------------------------------------------------------------
// K1: row-projection. out1[r][h] = sum_k in[r][k] * w1[k][h]  (h < 24)
// Optionally a second output (fused k & v share the encoded read).
// block = 256 threads, 32 rows/block. thread -> (row = tid/8, 3 h-columns).
// ---------------------------------------------------------------------------
template <int NW>
__global__ __launch_bounds__(256) void proj_kernel(
    const float* __restrict__ in, const float* __restrict__ w1,
    const float* __restrict__ w2, float* __restrict__ out1,
    float* __restrict__ out2) {
  __shared__ __align__(16) float s_in[32][68];
  __shared__ __align__(16) float s_w1[24][68];
  __shared__ __align__(16) float s_w2[(NW > 1) ? 24 : 1][68];

  const int tid = threadIdx.x;
  const int row = tid >> 3;  // 0..31
  const int hg = tid & 7;    // 0..7
  const int h0 = hg * 3;     // 0,3,...,21
  const long gr = (long)blockIdx.x * 32 + row;

  float acc1[3] = {0.f, 0.f, 0.f};
  float acc2[3] = {0.f, 0.f, 0.f};

  for (int kc = 0; kc < D_; kc += 64) {
    // stage 64 K-columns of the 32 input rows (coalesced float4)
    const float4* gin = (const float4*)(in + gr * D_ + kc);
    float4 a0 = gin[hg];
    float4 a1 = gin[hg + 8];
    *(float4*)&s_in[row][4 * hg] = a0;
    *(float4*)&s_in[row][4 * hg + 32] = a1;
    // stage w chunk transposed: global reads are perfectly contiguous
    for (int i = tid; i < 64 * H_; i += 256) {
      int k = i / H_, h = i - k * H_;
      s_w1[h][k] = w1[(kc + k) * H_ + h];
    }
    if constexpr (NW > 1) {
      for (int i = tid; i < 64 * H_; i += 256) {
        int k = i / H_, h = i - k * H_;
        s_w2[h][k] = w2[(kc + k) * H_ + h];
      }
    }
    __syncthreads();
#pragma unroll
    for (int kq = 0; kq < 16; ++kq) {
      float4 x = *(const float4*)&s_in[row][4 * kq];
#pragma unroll
      for (int i = 0; i < 3; ++i) {
        float4 wv = *(const float4*)&s_w1[h0 + i][4 * kq];
        acc1[i] = fmaf(x.x, wv.x, acc1[i]);
        acc1[i] = fmaf(x.y, wv.y, acc1[i]);
        acc1[i] = fmaf(x.z, wv.z, acc1[i]);
        acc1[i] = fmaf(x.w, wv.w, acc1[i]);
      }
      if constexpr (NW > 1) {
#pragma unroll
        for (int i = 0; i < 3; ++i) {
          float4 wv = *(const float4*)&s_w2[h0 + i][4 * kq];
          acc2[i] = fmaf(x.x, wv.x, acc2[i]);
          acc2[i] = fmaf(x.y, wv.y, acc2[i]);
          acc2[i] = fmaf(x.z, wv.z, acc2[i]);
          acc2[i] = fmaf(x.w, wv.w, acc2[i]);
        }
      }
    }
    __syncthreads();
  }
#pragma unroll
  for (int i = 0; i < 3; ++i) out1[gr * H_ + h0 + i] = acc1[i];
  if constexpr (NW > 1) {
#pragma unroll
    for (int i = 0; i < 3; ++i) out2[gr * H_ + h0 + i] = acc2[i];
  }
}

// ---------------------------------------------------------------------------
// K2: column sums d[s] = sum_t exp(q[t]·k[s]).  No max-subtraction needed:
// scores ~ N(0,2), global max < ~15, exp() safe in fp32.
// grid (S/256, B, T/512); thread owns one s (k-row in 24 regs), iterates t
// with q staged in LDS (all lanes read the same q[t] -> pure broadcast).
// Writes partial sums per t-chunk (deterministic, no atomics).
// ---------------------------------------------------------------------------
__global__ __launch_bounds__(256) void colsum_kernel(
    const float* __restrict__ q, const float* __restrict__ kk,
    float* __restrict__ dpart) {
  __shared__ __align__(16) float s_q[128 * 24];
  const int tid = threadIdx.x;
  const int b = blockIdx.y;
  const int s = blockIdx.x * 256 + tid;
  const int t0 = blockIdx.z * 512;

  const float* krow = kk + ((long)b * S_ + s) * H_;
  float kr[24];
#pragma unroll
  for (int j = 0; j < 6; ++j) {
    float4 v = *(const float4*)(krow + 4 * j);
    kr[4 * j] = v.x; kr[4 * j + 1] = v.y; kr[4 * j + 2] = v.z; kr[4 * j + 3] = v.w;
  }

  float d = 0.f;
  for (int tc = 0; tc < 4; ++tc) {
    const float4* gq = (const float4*)(q + ((long)b * T_ + t0 + tc * 128) * H_);
#pragma unroll
    for (int j = 0; j < 3; ++j) ((float4*)s_q)[tid + 256 * j] = gq[tid + 256 * j];
    __syncthreads();
    for (int tt = 0; tt < 128; ++tt) {
      const float* qr = s_q + tt * 24;
      float sc = 0.f;
#pragma unroll
      for (int j = 0; j < 6; ++j) {
        float4 x = *(const float4*)(qr + 4 * j);
        sc = fmaf(x.x, kr[4 * j], sc);
        sc = fmaf(x.y, kr[4 * j + 1], sc);
        sc = fmaf(x.z, kr[4 * j + 2], sc);
        sc = fmaf(x.w, kr[4 * j + 3], sc);
      }
      d += __expf(sc);
    }
    __syncthreads();
  }
  dpart[(long)blockIdx.z * BS_ + b * S_ + s] = d;
}

// K2b: reduce the 4 t-chunk partials and invert.
__global__ __launch_bounds__(256) void dinv_kernel(const float* __restrict__ dpart,
                                                   float* __restrict__ dinv) {
  int i = blockIdx.x * 256 + threadIdx.x;  // < 32768
  float d = dpart[i] + dpart[BS_ + i] + dpart[2 * BS_ + i] + dpart[3 * BS_ + i];
  dinv[i] = 1.0f / d;
}

// ---------------------------------------------------------------------------
// K3: h1[t,h] = sum_s exp(q[t]·k[s]) * (v[s,h]/d[s]).  Scores recomputed
// (3.2 GFLOP, cheaper than writing/reading a 268MB score matrix).
// grid (T/128, B, 4 s-chunks), block 128; thread owns one t (q in 24 regs,
// acc in 24 regs); k and dinv-prescaled v staged in LDS, broadcast reads.
// s split 4-way into separate partial buffers for occupancy (no atomics).
// ---------------------------------------------------------------------------
__global__ __launch_bounds__(128) void attn_kernel(
    const float* __restrict__ q, const float* __restrict__ kk,
    const float* __restrict__ vv, const float* __restrict__ dinv,
    float* __restrict__ h1p) {
  __shared__ __align__(16) float s_k[64 * 24];
  __shared__ __align__(16) float s_v[64 * 24];
  const int tid = threadIdx.x;
  const int b = blockIdx.y;
  const long t = (long)blockIdx.x * 128 + tid;
  const int s0 = blockIdx.z * 512;

  const float* qrow = q + ((long)b * T_ + t) * H_;
  float qr[24];
#pragma unroll
  for (int j = 0; j < 6; ++j) {
    float4 v = *(const float4*)(qrow + 4 * j);
    qr[4 * j] = v.x; qr[4 * j + 1] = v.y; qr[4 * j + 2] = v.z; qr[4 * j + 3] = v.w;
  }
  float acc[24];
#pragma unroll
  for (int j = 0; j < 24; ++j) acc[j] = 0.f;

  for (int sc_ = 0; sc_ < 8; ++sc_) {
    const int sbase = s0 + sc_ * 64;
    const float4* gk = (const float4*)(kk + ((long)b * S_ + sbase) * H_);
    const float4* gv = (const float4*)(vv + ((long)b * S_ + sbase) * H_);
#pragma unroll
    for (int j = 0; j < 3; ++j) {
      int f4 = tid + 128 * j;  // 0..383 ; 6 float4 per s-row (24 floats)
      ((float4*)s_k)[f4] = gk[f4];
      float4 vx = gv[f4];
      float dv = dinv[b * S_ + sbase + f4 / 6];
      vx.x *= dv; vx.y *= dv; vx.z *= dv; vx.w *= dv;
      ((float4*)s_v)[f4] = vx;
    }
    __syncthreads();
    for (int ss = 0; ss < 64; ++ss) {
      const float* krow = s_k + ss * 24;
      float sc = 0.f;
#pragma unroll
      for (int j = 0; j < 6; ++j) {
        float4 x = *(const float4*)(krow + 4 * j);
        sc = fmaf(x.x, qr[4 * j], sc);
        sc = fmaf(x.y, qr[4 * j + 1], sc);
        sc = fmaf(x.z, qr[4 * j + 2], sc);
        sc = fmaf(x.w, qr[4 * j + 3], sc);
      }
      float p = __expf(sc);
      const float* vrow = s_v + ss * 24;
#pragma unroll
      for (int j = 0; j < 6; ++j) {
        float4 x = *(const float4*)(vrow + 4 * j);
        acc[4 * j] = fmaf(p, x.x, acc[4 * j]);
        acc[4 * j + 1] = fmaf(p, x.y, acc[4 * j + 1]);
        acc[4 * j + 2] = fmaf(p, x.z, acc[4 * j + 2]);
        acc[4 * j + 3] = fmaf(p, x.w, acc[4 * j + 3]);
      }
    }
    __syncthreads();
  }
  float* o = h1p + (long)blockIdx.z * QN_ + ((long)b * T_ + t) * H_;
#pragma unroll
  for (int j = 0; j < 6; ++j) {
    float4 x = make_float4(acc[4 * j], acc[4 * j + 1], acc[4 * j + 2], acc[4 * j + 3]);
    *(float4*)(o + 4 * j) = x;
  }
}

// ---------------------------------------------------------------------------
// K4: out[r][d] = sum_h h1[r][h] * wh[h][d].  Folds the 4-way h1 partial
// reduce. block = 256, 16 rows/block (384 staged floats -> strided loop,
// NOT a tid<384 guard: block only has 256 threads). 4 d-chunks of 256;
// wh column slice in 24 regs (coalesced, L2-hot), h1 row broadcast from LDS.
// ---------------------------------------------------------------------------
__global__ __launch_bounds__(256) void out_kernel(const float* __restrict__ h1p,
                                                  const float* __restrict__ wh,
                                                  float* __restrict__ out) {
  __shared__ __align__(16) float s_h1[16 * 24];
  const int tid = threadIdx.x;
  const long rbase = (long)blockIdx.x * 16;
  for (int i = tid; i < 16 * H_; i += 256) {
    long off = rbase * H_ + i;
    s_h1[i] = h1p[off] + h1p[off + QN_] + h1p[off + 2L * QN_] + h1p[off + 3L * QN_];
  }
  __syncthreads();
  for (int c = 0; c < 4; ++c) {
    const int dd = c * 256 + tid;
    float wr[24];
#pragma unroll
    for (int h = 0; h < 24; ++h) wr[h] = wh[h * D_ + dd];
#pragma unroll 1
    for (int r = 0; r < 16; ++r) {
      float a = 0.f;
#pragma unroll
      for (int j = 0; j < 6; ++j) {
        float4 hv = *(const float4*)(s_h1 + r * 24 + 4 * j);
        a = fmaf(hv.x, wr[4 * j], a);
        a = fmaf(hv.y, wr[4 * j + 1], a);
        a = fmaf(hv.z, wr[4 * j + 2], a);
        a = fmaf(hv.w, wr[4 * j + 3], a);
      }
      out[(rbase + r) * D_ + dd] = a;
    }
  }
}

// ---------------------------------------------------------------------------
extern "C" void kernel_launch(void* const* d_in, const int* in_sizes, int n_in,
                              void* d_out, int out_size, void* d_ws,
                              size_t ws_size, hipStream_t stream) {
  const float* encoded = (const float*)d_in[0];
  const float* text = (const float*)d_in[1];
  const float* wq = (const float*)d_in[2];
  const float* wk = (const float*)d_in[3];
  const float* wv = (const float*)d_in[4];
  const float* wh = (const float*)d_in[5];
  float* out = (float*)d_out;

  // workspace layout (floats): ~21.6 MiB total
  float* ws = (float*)d_ws;
  float* q = ws;                   // 786432
  float* kk = q + QN_;             // 786432
  float* vv = kk + QN_;            // 786432
  float* dpart = vv + QN_;         // 4*32768
  float* dinv = dpart + 4 * BS_;   // 32768
  float* h1p = dinv + BS_;         // 4*786432

  proj_kernel<1><<<NROW_ / 32, 256, 0, stream>>>(text, wq, nullptr, q, nullptr);
  proj_kernel<2><<<NROW_ / 32, 256, 0, stream>>>(encoded, wk, wv, kk, vv);
  colsum_kernel<<<dim3(S_ / 256, B_, 4), 256, 0, stream>>>(q, kk, dpart);
  dinv_kernel<<<BS_ / 256, 256, 0, stream>>>(dpart, dinv);
  attn_kernel<<<dim3(T_ / 128, B_, 4), 128, 0, stream>>>(q, kk, vv, dinv, h1p);
  out_kernel<<<NROW_ / 16, 256, 0, stream>>>(h1p, wh, out);
}

// Round 3
// 308.116 us; speedup vs baseline: 1.7604x; 1.7604x over previous
//
#include <hip/hip_runtime.h>
#include <hip/hip_bf16.h>

// Problem: B=16, T=S=2048, D=1024, H=24
#define B_ 16
#define T_ 2048
#define S_ 2048
#define D_ 1024
#define H_ 24
#define NROW_ (B_ * T_)            // 32768 rows
#define BS_ (B_ * S_)              // 32768
#define QN32_ ((size_t)NROW_ * 32) // padded projection / h1-part elements

typedef float f32x16 __attribute__((ext_vector_type(16)));
typedef __bf16 bf16x8 __attribute__((ext_vector_type(8)));

union B8u { int4 i; bf16x8 b; };
__device__ inline bf16x8 pun(int4 v) { B8u u; u.i = v; return u.b; }

__device__ inline ushort f2bf(float f) {  // RNE fp32->bf16
  uint u = __float_as_uint(f);
  u += 0x7fffu + ((u >> 16) & 1u);
  return (ushort)(u >> 16);
}
__device__ inline float bf2f(ushort u) { return __uint_as_float(((uint)u) << 16); }

__device__ inline f32x16 mfma32(bf16x8 a, bf16x8 b, f32x16 c) {
  return __builtin_amdgcn_mfma_f32_32x32x16_bf16(a, b, c, 0, 0, 0);
}

// ---------------------------------------------------------------------------
// K1: row-projection (fp32 VALU). out1 = bf16 zero-padded [row][32].
// NW=2 additionally writes out2 = fp32 compact [row][24] (the v matrix).
// ---------------------------------------------------------------------------
template <int NW>
__global__ __launch_bounds__(256) void proj_kernel(
    const float* __restrict__ in, const float* __restrict__ w1,
    const float* __restrict__ w2, ushort* __restrict__ out1,
    float* __restrict__ out2) {
  __shared__ __align__(16) float s_in[32][68];
  __shared__ __align__(16) float s_w1[24][68];
  __shared__ __align__(16) float s_w2[(NW > 1) ? 24 : 1][68];

  const int tid = threadIdx.x;
  const int row = tid >> 3;
  const int hg = tid & 7;
  const int h0 = hg * 3;
  const long gr = (long)blockIdx.x * 32 + row;

  float acc1[3] = {0.f, 0.f, 0.f};
  float acc2[3] = {0.f, 0.f, 0.f};

  for (int kc = 0; kc < D_; kc += 64) {
    const float4* gin = (const float4*)(in + gr * D_ + kc);
    float4 a0 = gin[hg];
    float4 a1 = gin[hg + 8];
    *(float4*)&s_in[row][4 * hg] = a0;
    *(float4*)&s_in[row][4 * hg + 32] = a1;
    for (int i = tid; i < 64 * H_; i += 256) {
      int k = i / H_, h = i - k * H_;
      s_w1[h][k] = w1[(kc + k) * H_ + h];
    }
    if constexpr (NW > 1) {
      for (int i = tid; i < 64 * H_; i += 256) {
        int k = i / H_, h = i - k * H_;
        s_w2[h][k] = w2[(kc + k) * H_ + h];
      }
    }
    __syncthreads();
#pragma unroll
    for (int kq = 0; kq < 16; ++kq) {
      float4 x = *(const float4*)&s_in[row][4 * kq];
#pragma unroll
      for (int i = 0; i < 3; ++i) {
        float4 wv = *(const float4*)&s_w1[h0 + i][4 * kq];
        acc1[i] = fmaf(x.x, wv.x, acc1[i]);
        acc1[i] = fmaf(x.y, wv.y, acc1[i]);
        acc1[i] = fmaf(x.z, wv.z, acc1[i]);
        acc1[i] = fmaf(x.w, wv.w, acc1[i]);
      }
      if constexpr (NW > 1) {
#pragma unroll
        for (int i = 0; i < 3; ++i) {
          float4 wv = *(const float4*)&s_w2[h0 + i][4 * kq];
          acc2[i] = fmaf(x.x, wv.x, acc2[i]);
          acc2[i] = fmaf(x.y, wv.y, acc2[i]);
          acc2[i] = fmaf(x.z, wv.z, acc2[i]);
          acc2[i] = fmaf(x.w, wv.w, acc2[i]);
        }
      }
    }
    __syncthreads();
  }
#pragma unroll
  for (int i = 0; i < 3; ++i) out1[gr * 32 + h0 + i] = f2bf(acc1[i]);
  if (hg == 7) {  // zero-pad h 24..31
    ushort4 z4 = {0, 0, 0, 0};
    *(ushort4*)&out1[gr * 32 + 24] = z4;
    *(ushort4*)&out1[gr * 32 + 28] = z4;
  }
  if constexpr (NW > 1) {
#pragma unroll
    for (int i = 0; i < 3; ++i) out2[gr * H_ + h0 + i] = acc2[i];
  }
}

// ---------------------------------------------------------------------------
// Pass 1: d[b,s] = sum_t exp(q_t . k_s) via un-swapped MFMA.
// C[r=t][c=s]: lane owns one s-column (c = lane&31); sum 16 regs + xor32.
// grid (S/128, B, 4 t-parts); block 256 = 4 waves (one 32-s chunk each).
// ---------------------------------------------------------------------------
__global__ __launch_bounds__(256) void colsum_mfma(
    const ushort* __restrict__ qb, const ushort* __restrict__ kb,
    float* __restrict__ dpart) {
  __shared__ __align__(16) ushort sQ[4 * 32 * 8];  // [hslot][t][8]
  const int tid = threadIdx.x;
  const int lane = tid & 63;
  const int lo = lane & 31, hi = lane >> 5;
  const int w = tid >> 6;
  const int b = blockIdx.y;
  const int s0 = blockIdx.x * 128 + w * 32;
  const int tpart = blockIdx.z;

  const ushort* krow = kb + ((size_t)b * S_ + s0 + lo) * 32;
  bf16x8 k0 = pun(*(const int4*)(krow + hi * 8));
  bf16x8 k1 = pun(*(const int4*)(krow + 16 + hi * 8));

  float dl = 0.f;
  for (int tc = 0; tc < 16; ++tc) {
    const int tbase = tpart * 512 + tc * 32;
    if (tid < 128) {
      int t = tid >> 2, j = tid & 3;
      *(int4*)&sQ[j * 256 + t * 8] =
          *(const int4*)(qb + ((size_t)b * T_ + tbase + t) * 32 + j * 8);
    }
    __syncthreads();
    bf16x8 qa = pun(*(const int4*)&sQ[hi * 256 + lo * 8]);
    bf16x8 qc = pun(*(const int4*)&sQ[(2 + hi) * 256 + lo * 8]);
    f32x16 c = {};
    c = mfma32(qa, k0, c);
    c = mfma32(qc, k1, c);
#pragma unroll
    for (int r = 0; r < 16; ++r) dl += __expf(c[r]);
    __syncthreads();
  }
  dl += __shfl_xor(dl, 32);
  if (hi == 0) dpart[(size_t)tpart * BS_ + (size_t)b * S_ + s0 + lo] = dl;
}

// K2b: reduce 4 t-part partials and invert.
__global__ __launch_bounds__(256) void dinv_kernel(const float* __restrict__ dpart,
                                                   float* __restrict__ dinv) {
  int i = blockIdx.x * 256 + threadIdx.x;
  float d = dpart[i] + dpart[BS_ + i] + dpart[2 * BS_ + i] + dpart[3 * BS_ + i];
  dinv[i] = 1.0f / d;
}

// ---------------------------------------------------------------------------
// vscale: vsT[b][h][s] = bf16(v[b][s][h] * dinv[b][s]), h padded to 32.
// ---------------------------------------------------------------------------
__global__ __launch_bounds__(256) void vscale_kernel(
    const float* __restrict__ vv, const float* __restrict__ dinv,
    ushort* __restrict__ vsT) {
  int gid = blockIdx.x * 256 + threadIdx.x;  // < 16*32*512
  int s4 = gid & 511;
  int h = (gid >> 9) & 31;
  int b = gid >> 14;
  int s0 = s4 * 4;
  ushort4 ov;
  if (h < H_) {
    const float* vp = vv + ((size_t)b * S_ + s0) * H_ + h;
    const float* dp = dinv + (size_t)b * S_ + s0;
    ov.x = f2bf(vp[0 * H_] * dp[0]);
    ov.y = f2bf(vp[1 * H_] * dp[1]);
    ov.z = f2bf(vp[2 * H_] * dp[2]);
    ov.w = f2bf(vp[3 * H_] * dp[3]);
  } else {
    ov.x = ov.y = ov.z = ov.w = 0;
  }
  *(ushort4*)&vsT[((size_t)b * 32 + h) * S_ + s0] = ov;
}

// ---------------------------------------------------------------------------
// Pass 2: h1[t,h] = sum_s exp(q_t.k_s) * vs[s,h]  (vs = v/d, pre-scaled).
// Swapped QK^T: C' = mfma(K,Q) -> P'[s][t] (lane owns t = lane&31).
// P' -> PV A-operand in-register: 8x v_cvt_pk_bf16_f32 + 4x permlane32_swap.
// V B-operand from vsT via conflict-free [slot][32][16B] LDS tiles.
// grid (T/128, B, 4 s-parts); block 256 = 4 waves; h1 partials bf16.
// ---------------------------------------------------------------------------
__global__ __launch_bounds__(256) void attn_mfma(
    const ushort* __restrict__ qb, const ushort* __restrict__ kb,
    const ushort* __restrict__ vsT, ushort* __restrict__ h1p) {
  __shared__ __align__(16) ushort sK[4 * 32 * 8];  // [hslot][s][8]
  __shared__ __align__(16) ushort sV[4 * 32 * 8];  // [sslot][h][8]
  const int tid = threadIdx.x;
  const int lane = tid & 63;
  const int lo = lane & 31, hi = lane >> 5;
  const int w = tid >> 6;
  const int b = blockIdx.y;
  const int t0 = blockIdx.x * 128 + w * 32;
  const int spart = blockIdx.z;

  const ushort* qrow = qb + ((size_t)b * T_ + t0 + lo) * 32;
  bf16x8 q0 = pun(*(const int4*)(qrow + hi * 8));
  bf16x8 q1 = pun(*(const int4*)(qrow + 16 + hi * 8));

  f32x16 hacc = {};
  for (int sc = 0; sc < 16; ++sc) {
    const int sbase = spart * 512 + sc * 32;
    if (tid < 128) {
      int s = tid >> 2, j = tid & 3;
      *(int4*)&sK[j * 256 + s * 8] =
          *(const int4*)(kb + ((size_t)b * S_ + sbase + s) * 32 + j * 8);
    } else {
      int i2 = tid - 128;
      int h = i2 >> 2, q = i2 & 3;
      *(int4*)&sV[q * 256 + h * 8] =
          *(const int4*)(vsT + ((size_t)b * 32 + h) * S_ + sbase + q * 8);
    }
    __syncthreads();
    bf16x8 ka = pun(*(const int4*)&sK[hi * 256 + lo * 8]);
    bf16x8 kc = pun(*(const int4*)&sK[(2 + hi) * 256 + lo * 8]);
    bf16x8 va = pun(*(const int4*)&sV[hi * 256 + lo * 8]);
    bf16x8 vc = pun(*(const int4*)&sV[(2 + hi) * 256 + lo * 8]);
    f32x16 c = {};
    c = mfma32(ka, q0, c);
    c = mfma32(kc, q1, c);
    // P -> bf16 A-fragments (in-register transpose across lane halves)
    uint pk[8];
#pragma unroll
    for (int m = 0; m < 8; ++m) {
      float plo = __expf(c[2 * m]);
      float phi = __expf(c[2 * m + 1]);
      asm("v_cvt_pk_bf16_f32 %0, %1, %2" : "=v"(pk[m]) : "v"(plo), "v"(phi));
    }
    asm("v_permlane32_swap_b32 %0, %1" : "+v"(pk[0]), "+v"(pk[2]));
    asm("v_permlane32_swap_b32 %0, %1" : "+v"(pk[1]), "+v"(pk[3]));
    asm("v_permlane32_swap_b32 %0, %1" : "+v"(pk[4]), "+v"(pk[6]));
    asm("v_permlane32_swap_b32 %0, %1" : "+v"(pk[5]), "+v"(pk[7]));
    int4 f0 = make_int4(pk[0], pk[1], pk[2], pk[3]);  // s 0..15 of chunk
    int4 f1 = make_int4(pk[4], pk[5], pk[6], pk[7]);  // s 16..31
    hacc = mfma32(pun(f0), va, hacc);
    hacc = mfma32(pun(f1), vc, hacc);
    __syncthreads();
  }
  ushort* o = h1p + (size_t)spart * QN32_ + (size_t)b * T_ * 32;
#pragma unroll
  for (int r = 0; r < 16; ++r) {
    int trow = t0 + (r & 3) + 8 * (r >> 2) + 4 * hi;
    o[(size_t)trow * 32 + lo] = f2bf(hacc[r]);
  }
}

// ---------------------------------------------------------------------------
// K4: out[r][d] = sum_h h1[r][h] * wh[h][d]; folds 4 bf16 s-part partials.
// ---------------------------------------------------------------------------
__global__ __launch_bounds__(256) void out_kernel(const ushort* __restrict__ h1p,
                                                  const float* __restrict__ wh,
                                                  float* __restrict__ out) {
  __shared__ __align__(16) float s_h1[16 * 24];
  const int tid = threadIdx.x;
  const long rbase = (long)blockIdx.x * 16;
  for (int i = tid; i < 16 * H_; i += 256) {
    int r = i / 24, h = i - r * 24;
    size_t off = (size_t)(rbase + r) * 32 + h;
    s_h1[i] = bf2f(h1p[off]) + bf2f(h1p[off + QN32_]) +
              bf2f(h1p[off + 2 * QN32_]) + bf2f(h1p[off + 3 * QN32_]);
  }
  __syncthreads();
  for (int c = 0; c < 4; ++c) {
    const int dd = c * 256 + tid;
    float wr[24];
#pragma unroll
    for (int h = 0; h < 24; ++h) wr[h] = wh[h * D_ + dd];
#pragma unroll 1
    for (int r = 0; r < 16; ++r) {
      float a = 0.f;
#pragma unroll
      for (int j = 0; j < 6; ++j) {
        float4 hv = *(const float4*)(s_h1 + r * 24 + 4 * j);
        a = fmaf(hv.x, wr[4 * j], a);
        a = fmaf(hv.y, wr[4 * j + 1], a);
        a = fmaf(hv.z, wr[4 * j + 2], a);
        a = fmaf(hv.w, wr[4 * j + 3], a);
      }
      out[(rbase + r) * D_ + dd] = a;
    }
  }
}

// ---------------------------------------------------------------------------
extern "C" void kernel_launch(void* const* d_in, const int* in_sizes, int n_in,
                              void* d_out, int out_size, void* d_ws,
                              size_t ws_size, hipStream_t stream) {
  const float* encoded = (const float*)d_in[0];
  const float* text = (const float*)d_in[1];
  const float* wq = (const float*)d_in[2];
  const float* wk = (const float*)d_in[3];
  const float* wv = (const float*)d_in[4];
  const float* wh = (const float*)d_in[5];
  float* out = (float*)d_out;

  // workspace layout: 17.6 MiB total (proven budget 21.6 MiB)
  ushort* qb = (ushort*)d_ws;              // [B][T][32] bf16  (2 MiB)
  ushort* kbuf = qb + QN32_;               // [B][S][32] bf16  (2 MiB)
  float* vv = (float*)(kbuf + QN32_);      // [B][S][24] f32   (3 MiB)
  float* dpart = vv + (size_t)BS_ * H_;    // [4][B*S] f32     (0.5 MiB)
  float* dinv = dpart + 4 * BS_;           // [B*S] f32        (0.13 MiB)
  ushort* vsT = (ushort*)(dinv + BS_);     // [B][32][S] bf16  (2 MiB)
  ushort* h1p = vsT + (size_t)B_ * 32 * S_;// [4][B][T][32] bf16 (8 MiB)

  proj_kernel<1><<<NROW_ / 32, 256, 0, stream>>>(text, wq, nullptr, qb, nullptr);
  proj_kernel<2><<<NROW_ / 32, 256, 0, stream>>>(encoded, wk, wv, kbuf, vv);
  colsum_mfma<<<dim3(S_ / 128, B_, 4), 256, 0, stream>>>(qb, kbuf, dpart);
  dinv_kernel<<<BS_ / 256, 256, 0, stream>>>(dpart, dinv);
  vscale_kernel<<<(B_ * 32 * (S_ / 4)) / 256, 256, 0, stream>>>(vv, dinv, vsT);
  attn_mfma<<<dim3(T_ / 128, B_, 4), 256, 0, stream>>>(qb, kbuf, vsT, h1p);
  out_kernel<<<NROW_ / 16, 256, 0, stream>>>(h1p, wh, out);
}

// Round 5
// 201.852 us; speedup vs baseline: 2.6872x; 1.5264x over previous
//
#include <hip/hip_runtime.h>
#include <hip/hip_bf16.h>

// Problem: B=16, T=S=2048, D=1024, H=24
#define B_ 16
#define T_ 2048
#define S_ 2048
#define D_ 1024
#define H_ 24
#define NROW_ (B_ * T_)            // 32768 rows
#define BS_ (B_ * S_)              // 32768
#define QN32_ ((size_t)NROW_ * 32) // padded projection / h1-part elements

typedef float f32x16 __attribute__((ext_vector_type(16)));
typedef __bf16 bf16x8 __attribute__((ext_vector_type(8)));

union B8u { int4 i; bf16x8 b; };
__device__ inline bf16x8 pun(int4 v) { B8u u; u.i = v; return u.b; }

__device__ inline ushort f2bf(float f) {  // RNE fp32->bf16
  uint u = __float_as_uint(f);
  u += 0x7fffu + ((u >> 16) & 1u);
  return (ushort)(u >> 16);
}
__device__ inline float bf2f(ushort u) { return __uint_as_float(((uint)u) << 16); }

__device__ inline f32x16 mfma32(bf16x8 a, bf16x8 b, f32x16 c) {
  return __builtin_amdgcn_mfma_f32_32x32x16_bf16(a, b, c, 0, 0, 0);
}

__device__ inline uint cvtpk(float a, float b) {
  uint r;
  asm("v_cvt_pk_bf16_f32 %0, %1, %2" : "=v"(r) : "v"(a), "v"(b));
  return r;
}

// ---------------------------------------------------------------------------
// K1 (MFMA): row-projection GEMM [32768x1024]x[1024x32pad].
// A-path: NO LDS — each lane streams its own row's k-octets from global,
// converts to bf16 in-register, depth-4 rotating buffer (8 loads in flight).
// B-path: weights staged once per block into LDS in fragment order
// sW[k8][n][k&7] (k8 = k>>3, 0..127) -> B-frag for k-chunk c is one
// ds_read_b128 at octet k8 = 2c + hi   (BUG in R4: used octet c, no hi).
// Padded cols 24..31 are zero -> outputs self-pad.
// block=256 (4 waves x 32 rows = 128 rows/block), grid=256.
// NW=2 fuses k and v (shared A stream); v written fp32 compact [row][24].
// ---------------------------------------------------------------------------
template <int NW>
__global__ __launch_bounds__(256) void proj_mfma(
    const float* __restrict__ in, const float* __restrict__ w1,
    const float* __restrict__ w2, ushort* __restrict__ out1,
    float* __restrict__ out2) {
  __shared__ __align__(16) ushort sW1[128 * 256];                   // 64 KiB
  __shared__ __align__(16) ushort sW2[(NW > 1) ? 128 * 256 : 8];    // 64 KiB

  const int tid = threadIdx.x;
  // ---- stage weights in fragment order (one-time) ----
  {
    const int n = tid & 31;
    const int k8b = tid >> 5;  // 0..7
    for (int it = 0; it < 16; ++it) {
      const int k8 = k8b * 16 + it;  // 0..127
      ushort tmp[8];
#pragma unroll
      for (int j = 0; j < 8; ++j) {
        float v = (n < H_) ? w1[(k8 * 8 + j) * H_ + n] : 0.f;
        tmp[j] = f2bf(v);
      }
      *(int4*)&sW1[k8 * 256 + n * 8] = *(const int4*)tmp;
      if constexpr (NW > 1) {
        ushort tmp2[8];
#pragma unroll
        for (int j = 0; j < 8; ++j) {
          float v = (n < H_) ? w2[(k8 * 8 + j) * H_ + n] : 0.f;
          tmp2[j] = f2bf(v);
        }
        *(int4*)&sW2[k8 * 256 + n * 8] = *(const int4*)tmp2;
      }
    }
  }
  __syncthreads();

  const int lane = tid & 63;
  const int lo = lane & 31, hi = lane >> 5;
  const int w = tid >> 6;
  const long rowbase = (long)blockIdx.x * 128 + w * 32;
  const float* inrow = in + (rowbase + lo) * D_ + hi * 8;

  float4 bufA[4], bufB[4];
#pragma unroll
  for (int j = 0; j < 4; ++j) {
    bufA[j] = *(const float4*)(inrow + j * 16);
    bufB[j] = *(const float4*)(inrow + j * 16 + 4);
  }

  f32x16 acc = {};
  f32x16 acc2 = {};
  for (int g = 0; g < 16; ++g) {
#pragma unroll
    for (int j = 0; j < 4; ++j) {
      const int c = g * 4 + j;  // k-chunk (K=16 each)
      float4 fa = bufA[j], fb = bufB[j];
      if (g < 15) {  // prefetch chunk c+4 (guard: stay in-bounds)
        bufA[j] = *(const float4*)(inrow + (c + 4) * 16);
        bufB[j] = *(const float4*)(inrow + (c + 4) * 16 + 4);
      }
      uint pk0 = cvtpk(fa.x, fa.y), pk1 = cvtpk(fa.z, fa.w);
      uint pk2 = cvtpk(fb.x, fb.y), pk3 = cvtpk(fb.z, fb.w);
      bf16x8 a = pun(make_int4(pk0, pk1, pk2, pk3));
      bf16x8 b1 = pun(*(const int4*)&sW1[(2 * c + hi) * 256 + lo * 8]);
      acc = mfma32(a, b1, acc);
      if constexpr (NW > 1) {
        bf16x8 b2 = pun(*(const int4*)&sW2[(2 * c + hi) * 256 + lo * 8]);
        acc2 = mfma32(a, b2, acc2);
      }
    }
  }

  // epilogue: C col = lane&31 (=h), row = (r&3)+8*(r>>2)+4*hi
  ushort* o1 = out1 + rowbase * 32;
#pragma unroll
  for (int r = 0; r < 16; ++r) {
    int mrow = (r & 3) + 8 * (r >> 2) + 4 * hi;
    o1[(long)mrow * 32 + lo] = f2bf(acc[r]);
  }
  if constexpr (NW > 1) {
    if (lo < H_) {
#pragma unroll
      for (int r = 0; r < 16; ++r) {
        int mrow = (r & 3) + 8 * (r >> 2) + 4 * hi;
        out2[(rowbase + mrow) * H_ + lo] = acc2[r];
      }
    }
  }
}

// ---------------------------------------------------------------------------
// Pass 1: d[b,s] = sum_t exp(q_t . k_s) via un-swapped MFMA.
// C[r=t][c=s]: lane owns one s-column (c = lane&31); sum 16 regs + xor32.
// grid (S/128, B, 4 t-parts); block 256 = 4 waves (one 32-s chunk each).
// ---------------------------------------------------------------------------
__global__ __launch_bounds__(256) void colsum_mfma(
    const ushort* __restrict__ qb, const ushort* __restrict__ kb,
    float* __restrict__ dpart) {
  __shared__ __align__(16) ushort sQ[4 * 32 * 8];  // [hslot][t][8]
  const int tid = threadIdx.x;
  const int lane = tid & 63;
  const int lo = lane & 31, hi = lane >> 5;
  const int w = tid >> 6;
  const int b = blockIdx.y;
  const int s0 = blockIdx.x * 128 + w * 32;
  const int tpart = blockIdx.z;

  const ushort* krow = kb + ((size_t)b * S_ + s0 + lo) * 32;
  bf16x8 k0 = pun(*(const int4*)(krow + hi * 8));
  bf16x8 k1 = pun(*(const int4*)(krow + 16 + hi * 8));

  float dl = 0.f;
  for (int tc = 0; tc < 16; ++tc) {
    const int tbase = tpart * 512 + tc * 32;
    if (tid < 128) {
      int t = tid >> 2, j = tid & 3;
      *(int4*)&sQ[j * 256 + t * 8] =
          *(const int4*)(qb + ((size_t)b * T_ + tbase + t) * 32 + j * 8);
    }
    __syncthreads();
    bf16x8 qa = pun(*(const int4*)&sQ[hi * 256 + lo * 8]);
    bf16x8 qc = pun(*(const int4*)&sQ[(2 + hi) * 256 + lo * 8]);
    f32x16 c = {};
    c = mfma32(qa, k0, c);
    c = mfma32(qc, k1, c);
#pragma unroll
    for (int r = 0; r < 16; ++r) dl += __expf(c[r]);
    __syncthreads();
  }
  dl += __shfl_xor(dl, 32);
  if (hi == 0) dpart[(size_t)tpart * BS_ + (size_t)b * S_ + s0 + lo] = dl;
}

// K2b: reduce 4 t-part partials and invert.
__global__ __launch_bounds__(256) void dinv_kernel(const float* __restrict__ dpart,
                                                   float* __restrict__ dinv) {
  int i = blockIdx.x * 256 + threadIdx.x;
  float d = dpart[i] + dpart[BS_ + i] + dpart[2 * BS_ + i] + dpart[3 * BS_ + i];
  dinv[i] = 1.0f / d;
}

// ---------------------------------------------------------------------------
// vscale: vsT[b][h][s] = bf16(v[b][s][h] * dinv[b][s]), h padded to 32.
// ---------------------------------------------------------------------------
__global__ __launch_bounds__(256) void vscale_kernel(
    const float* __restrict__ vv, const float* __restrict__ dinv,
    ushort* __restrict__ vsT) {
  int gid = blockIdx.x * 256 + threadIdx.x;  // < 16*32*512
  int s4 = gid & 511;
  int h = (gid >> 9) & 31;
  int b = gid >> 14;
  int s0 = s4 * 4;
  ushort4 ov;
  if (h < H_) {
    const float* vp = vv + ((size_t)b * S_ + s0) * H_ + h;
    const float* dp = dinv + (size_t)b * S_ + s0;
    ov.x = f2bf(vp[0 * H_] * dp[0]);
    ov.y = f2bf(vp[1 * H_] * dp[1]);
    ov.z = f2bf(vp[2 * H_] * dp[2]);
    ov.w = f2bf(vp[3 * H_] * dp[3]);
  } else {
    ov.x = ov.y = ov.z = ov.w = 0;
  }
  *(ushort4*)&vsT[((size_t)b * 32 + h) * S_ + s0] = ov;
}

// ---------------------------------------------------------------------------
// Pass 2: h1[t,h] = sum_s exp(q_t.k_s) * vs[s,h]  (vs = v/d, pre-scaled).
// Swapped QK^T: C' = mfma(K,Q) -> P'[s][t]; P' -> PV A-operand in-register
// via cvt_pk_bf16 + permlane32_swap. grid (T/128, B, 4 s-parts).
// ---------------------------------------------------------------------------
__global__ __launch_bounds__(256) void attn_mfma(
    const ushort* __restrict__ qb, const ushort* __restrict__ kb,
    const ushort* __restrict__ vsT, ushort* __restrict__ h1p) {
  __shared__ __align__(16) ushort sK[4 * 32 * 8];  // [hslot][s][8]
  __shared__ __align__(16) ushort sV[4 * 32 * 8];  // [sslot][h][8]
  const int tid = threadIdx.x;
  const int lane = tid & 63;
  const int lo = lane & 31, hi = lane >> 5;
  const int w = tid >> 6;
  const int b = blockIdx.y;
  const int t0 = blockIdx.x * 128 + w * 32;
  const int spart = blockIdx.z;

  const ushort* qrow = qb + ((size_t)b * T_ + t0 + lo) * 32;
  bf16x8 q0 = pun(*(const int4*)(qrow + hi * 8));
  bf16x8 q1 = pun(*(const int4*)(qrow + 16 + hi * 8));

  f32x16 hacc = {};
  for (int sc = 0; sc < 16; ++sc) {
    const int sbase = spart * 512 + sc * 32;
    if (tid < 128) {
      int s = tid >> 2, j = tid & 3;
      *(int4*)&sK[j * 256 + s * 8] =
          *(const int4*)(kb + ((size_t)b * S_ + sbase + s) * 32 + j * 8);
    } else {
      int i2 = tid - 128;
      int h = i2 >> 2, q = i2 & 3;
      *(int4*)&sV[q * 256 + h * 8] =
          *(const int4*)(vsT + ((size_t)b * 32 + h) * S_ + sbase + q * 8);
    }
    __syncthreads();
    bf16x8 ka = pun(*(const int4*)&sK[hi * 256 + lo * 8]);
    bf16x8 kc = pun(*(const int4*)&sK[(2 + hi) * 256 + lo * 8]);
    bf16x8 va = pun(*(const int4*)&sV[hi * 256 + lo * 8]);
    bf16x8 vc = pun(*(const int4*)&sV[(2 + hi) * 256 + lo * 8]);
    f32x16 c = {};
    c = mfma32(ka, q0, c);
    c = mfma32(kc, q1, c);
    uint pk[8];
#pragma unroll
    for (int m = 0; m < 8; ++m) {
      float plo = __expf(c[2 * m]);
      float phi = __expf(c[2 * m + 1]);
      pk[m] = cvtpk(plo, phi);
    }
    asm("v_permlane32_swap_b32 %0, %1" : "+v"(pk[0]), "+v"(pk[2]));
    asm("v_permlane32_swap_b32 %0, %1" : "+v"(pk[1]), "+v"(pk[3]));
    asm("v_permlane32_swap_b32 %0, %1" : "+v"(pk[4]), "+v"(pk[6]));
    asm("v_permlane32_swap_b32 %0, %1" : "+v"(pk[5]), "+v"(pk[7]));
    int4 f0 = make_int4(pk[0], pk[1], pk[2], pk[3]);  // s 0..15 of chunk
    int4 f1 = make_int4(pk[4], pk[5], pk[6], pk[7]);  // s 16..31
    hacc = mfma32(pun(f0), va, hacc);
    hacc = mfma32(pun(f1), vc, hacc);
    __syncthreads();
  }
  ushort* o = h1p + (size_t)spart * QN32_ + (size_t)b * T_ * 32;
#pragma unroll
  for (int r = 0; r < 16; ++r) {
    int trow = t0 + (r & 3) + 8 * (r >> 2) + 4 * hi;
    o[(size_t)trow * 32 + lo] = f2bf(hacc[r]);
  }
}

// ---------------------------------------------------------------------------
// K4: out[r][d] = sum_h h1[r][h] * wh[h][d]; folds 4 bf16 s-part partials.
// ---------------------------------------------------------------------------
__global__ __launch_bounds__(256) void out_kernel(const ushort* __restrict__ h1p,
                                                  const float* __restrict__ wh,
                                                  float* __restrict__ out) {
  __shared__ __align__(16) float s_h1[16 * 24];
  const int tid = threadIdx.x;
  const long rbase = (long)blockIdx.x * 16;
  for (int i = tid; i < 16 * H_; i += 256) {
    int r = i / 24, h = i - r * 24;
    size_t off = (size_t)(rbase + r) * 32 + h;
    s_h1[i] = bf2f(h1p[off]) + bf2f(h1p[off + QN32_]) +
              bf2f(h1p[off + 2 * QN32_]) + bf2f(h1p[off + 3 * QN32_]);
  }
  __syncthreads();
  for (int c = 0; c < 4; ++c) {
    const int dd = c * 256 + tid;
    float wr[24];
#pragma unroll
    for (int h = 0; h < 24; ++h) wr[h] = wh[h * D_ + dd];
#pragma unroll 1
    for (int r = 0; r < 16; ++r) {
      float a = 0.f;
#pragma unroll
      for (int j = 0; j < 6; ++j) {
        float4 hv = *(const float4*)(s_h1 + r * 24 + 4 * j);
        a = fmaf(hv.x, wr[4 * j], a);
        a = fmaf(hv.y, wr[4 * j + 1], a);
        a = fmaf(hv.z, wr[4 * j + 2], a);
        a = fmaf(hv.w, wr[4 * j + 3], a);
      }
      out[(rbase + r) * D_ + dd] = a;
    }
  }
}

// ---------------------------------------------------------------------------
extern "C" void kernel_launch(void* const* d_in, const int* in_sizes, int n_in,
                              void* d_out, int out_size, void* d_ws,
                              size_t ws_size, hipStream_t stream) {
  const float* encoded = (const float*)d_in[0];
  const float* text = (const float*)d_in[1];
  const float* wq = (const float*)d_in[2];
  const float* wk = (const float*)d_in[3];
  const float* wv = (const float*)d_in[4];
  const float* wh = (const float*)d_in[5];
  float* out = (float*)d_out;

  // workspace layout: 17.6 MiB total (proven budget >= 22.6 MiB from R2)
  ushort* qb = (ushort*)d_ws;              // [B][T][32] bf16  (2 MiB)
  ushort* kbuf = qb + QN32_;               // [B][S][32] bf16  (2 MiB)
  float* vv = (float*)(kbuf + QN32_);      // [B][S][24] f32   (3 MiB)
  float* dpart = vv + (size_t)BS_ * H_;    // [4][B*S] f32     (0.5 MiB)
  float* dinv = dpart + 4 * BS_;           // [B*S] f32        (0.13 MiB)
  ushort* vsT = (ushort*)(dinv + BS_);     // [B][32][S] bf16  (2 MiB)
  ushort* h1p = vsT + (size_t)B_ * 32 * S_;// [4][B][T][32] bf16 (8 MiB)

  proj_mfma<1><<<NROW_ / 128, 256, 0, stream>>>(text, wq, nullptr, qb, nullptr);
  proj_mfma<2><<<NROW_ / 128, 256, 0, stream>>>(encoded, wk, wv, kbuf, vv);
  colsum_mfma<<<dim3(S_ / 128, B_, 4), 256, 0, stream>>>(qb, kbuf, dpart);
  dinv_kernel<<<BS_ / 256, 256, 0, stream>>>(dpart, dinv);
  vscale_kernel<<<(B_ * 32 * (S_ / 4)) / 256, 256, 0, stream>>>(vv, dinv, vsT);
  attn_mfma<<<dim3(T_ / 128, B_, 4), 256, 0, stream>>>(qb, kbuf, vsT, h1p);
  out_kernel<<<NROW_ / 16, 256, 0, stream>>>(h1p, wh, out);
}

// Round 6
// 186.583 us; speedup vs baseline: 2.9071x; 1.0818x over previous
//
#include <hip/hip_runtime.h>
#include <hip/hip_bf16.h>

// Problem: B=16, T=S=2048, D=1024, H=24
#define B_ 16
#define T_ 2048
#define S_ 2048
#define D_ 1024
#define H_ 24
#define NROW_ (B_ * T_)            // 32768 rows
#define BS_ (B_ * S_)              // 32768
#define QN32_ ((size_t)NROW_ * 32) // padded projection / h1-part elements

typedef float f32x16 __attribute__((ext_vector_type(16)));
typedef __bf16 bf16x8 __attribute__((ext_vector_type(8)));

union B8u { int4 i; bf16x8 b; };
__device__ inline bf16x8 pun(int4 v) { B8u u; u.i = v; return u.b; }

__device__ inline ushort f2bf(float f) {  // RNE fp32->bf16
  uint u = __float_as_uint(f);
  u += 0x7fffu + ((u >> 16) & 1u);
  return (ushort)(u >> 16);
}
__device__ inline float bf2f(ushort u) { return __uint_as_float(((uint)u) << 16); }

__device__ inline f32x16 mfma32(bf16x8 a, bf16x8 b, f32x16 c) {
  return __builtin_amdgcn_mfma_f32_32x32x16_bf16(a, b, c, 0, 0, 0);
}

__device__ inline uint cvtpk(float a, float b) {
  uint r;
  asm("v_cvt_pk_bf16_f32 %0, %1, %2" : "=v"(r) : "v"(a), "v"(b));
  return r;
}

// ---------------------------------------------------------------------------
// K1 (MFMA, R6 rewrite): row-projection GEMM [32768x1024]x[1024x24].
// R5 problem: per-lane-row global A-loads (4KB stride, 32B runs) -> latency/
// scatter-bound, 890 GB/s, all pipes <4%. Fix: coalesced A staging.
//   Per 64-col window: threads load 256B-contiguous runs (row=g>>4, f4=g&15),
//   cvt to bf16 in-reg, ds_write into fragment-order sA[k8][row^k8][8].
//   Read = [k8=2c+hi][row=lo] b128, consecutive-16B-per-lane (the proven
//   0-conflict pattern from attn). Double-buffered; loads for w+1 issued
//   before compute of w (T14 issue-early/write-late).
// Weights: LDS fragment-order [k8g][n<24][8] bf16 (48 KiB each); lanes
// lo>=24 read col 0 (dup, harmless) and epilogue forces pad cols to 0.
// LDS: proj<1> 80 KiB, proj<2> 128 KiB. block=256 (4 waves x 32 rows),
// grid=256. NW=2 fuses k and v; v written fp32 compact [row][24].
// ---------------------------------------------------------------------------
template <int NW>
__global__ __launch_bounds__(256) void proj_mfma(
    const float* __restrict__ in, const float* __restrict__ w1,
    const float* __restrict__ w2, ushort* __restrict__ out1,
    float* __restrict__ out2) {
  __shared__ __align__(16) ushort sA[2][8][128][8];                 // 32 KiB
  __shared__ __align__(16) ushort sW1[128 * 24 * 8];                // 48 KiB
  __shared__ __align__(16) ushort sW2[(NW > 1) ? 128 * 24 * 8 : 8]; // 48 KiB

  const int tid = threadIdx.x;
  // ---- stage weights in fragment order (one-time; coalesced 96B runs) ----
  for (int i = tid; i < 128 * 24; i += 256) {
    const int k8g = i / 24, n = i - k8g * 24;
    ushort t1[8];
#pragma unroll
    for (int j = 0; j < 8; ++j) t1[j] = f2bf(w1[(k8g * 8 + j) * H_ + n]);
    *(int4*)&sW1[i * 8] = *(const int4*)t1;
    if constexpr (NW > 1) {
      ushort t2[8];
#pragma unroll
      for (int j = 0; j < 8; ++j) t2[j] = f2bf(w2[(k8g * 8 + j) * H_ + n]);
      *(int4*)&sW2[i * 8] = *(const int4*)t2;
    }
  }

  const int lane = tid & 63;
  const int lo = lane & 31, hi = lane >> 5;
  const int w = tid >> 6;  // wave id: compute rows [w*32, w*32+32)
  const long rowbase = (long)blockIdx.x * 128;
  const int rowA = w * 32 + lo;

  // ---- prologue: stage window 0 into buf 0 ----
  {
    float4 fv[8];
#pragma unroll
    for (int i = 0; i < 8; ++i) {
      int g = tid + 256 * i, row = g >> 4, f4i = g & 15;
      fv[i] = *(const float4*)(in + (rowbase + row) * D_ + f4i * 4);
    }
#pragma unroll
    for (int i = 0; i < 8; ++i) {
      int g = tid + 256 * i, row = g >> 4, f4i = g & 15;
      int k8 = f4i >> 1, par = f4i & 1;
      uint p0 = cvtpk(fv[i].x, fv[i].y), p1 = cvtpk(fv[i].z, fv[i].w);
      *(uint2*)&sA[0][k8][row ^ k8][par * 4] = make_uint2(p0, p1);
    }
  }
  __syncthreads();

  f32x16 acc = {};
  f32x16 acc2 = {};
  const int ne = (lo < H_) ? lo : 0;  // dup col for pad lanes

  for (int win = 0; win < 16; ++win) {
    const int buf = win & 1;
    float4 fv[8];
    if (win < 15) {  // issue loads for next window (coalesced 256B runs)
#pragma unroll
      for (int i = 0; i < 8; ++i) {
        int g = tid + 256 * i, row = g >> 4, f4i = g & 15;
        fv[i] = *(const float4*)(in + (rowbase + row) * D_ + (win + 1) * 64 + f4i * 4);
      }
    }
    // compute current window (hides the load latency)
#pragma unroll
    for (int cl = 0; cl < 4; ++cl) {
      const int k8 = 2 * cl + hi;
      bf16x8 a = pun(*(const int4*)&sA[buf][k8][rowA ^ k8][0]);
      const int k8g = win * 8 + k8;
      bf16x8 b1 = pun(*(const int4*)&sW1[(k8g * 24 + ne) * 8]);
      acc = mfma32(a, b1, acc);
      if constexpr (NW > 1) {
        bf16x8 b2 = pun(*(const int4*)&sW2[(k8g * 24 + ne) * 8]);
        acc2 = mfma32(a, b2, acc2);
      }
    }
    if (win < 15) {  // write next window into the other buffer
#pragma unroll
      for (int i = 0; i < 8; ++i) {
        int g = tid + 256 * i, row = g >> 4, f4i = g & 15;
        int k8 = f4i >> 1, par = f4i & 1;
        uint p0 = cvtpk(fv[i].x, fv[i].y), p1 = cvtpk(fv[i].z, fv[i].w);
        *(uint2*)&sA[buf ^ 1][k8][row ^ k8][par * 4] = make_uint2(p0, p1);
      }
    }
    __syncthreads();
  }

  // epilogue: C col = lane&31 (=h), row = (r&3)+8*(r>>2)+4*hi; pad cols -> 0
  ushort* o1 = out1 + rowbase * 32;
#pragma unroll
  for (int r = 0; r < 16; ++r) {
    int mrow = w * 32 + (r & 3) + 8 * (r >> 2) + 4 * hi;
    o1[(long)mrow * 32 + lo] = (lo < H_) ? f2bf(acc[r]) : (ushort)0;
  }
  if constexpr (NW > 1) {
    if (lo < H_) {
#pragma unroll
      for (int r = 0; r < 16; ++r) {
        int mrow = w * 32 + (r & 3) + 8 * (r >> 2) + 4 * hi;
        out2[(rowbase + mrow) * H_ + lo] = acc2[r];
      }
    }
  }
}

// ---------------------------------------------------------------------------
// Pass 1: d[b,s] = sum_t exp(q_t . k_s) via un-swapped MFMA.
// C[r=t][c=s]: lane owns one s-column (c = lane&31); sum 16 regs + xor32.
// grid (S/128, B, 4 t-parts); block 256 = 4 waves (one 32-s chunk each).
// ---------------------------------------------------------------------------
__global__ __launch_bounds__(256) void colsum_mfma(
    const ushort* __restrict__ qb, const ushort* __restrict__ kb,
    float* __restrict__ dpart) {
  __shared__ __align__(16) ushort sQ[4 * 32 * 8];  // [hslot][t][8]
  const int tid = threadIdx.x;
  const int lane = tid & 63;
  const int lo = lane & 31, hi = lane >> 5;
  const int w = tid >> 6;
  const int b = blockIdx.y;
  const int s0 = blockIdx.x * 128 + w * 32;
  const int tpart = blockIdx.z;

  const ushort* krow = kb + ((size_t)b * S_ + s0 + lo) * 32;
  bf16x8 k0 = pun(*(const int4*)(krow + hi * 8));
  bf16x8 k1 = pun(*(const int4*)(krow + 16 + hi * 8));

  float dl = 0.f;
  for (int tc = 0; tc < 16; ++tc) {
    const int tbase = tpart * 512 + tc * 32;
    if (tid < 128) {
      int t = tid >> 2, j = tid & 3;
      *(int4*)&sQ[j * 256 + t * 8] =
          *(const int4*)(qb + ((size_t)b * T_ + tbase + t) * 32 + j * 8);
    }
    __syncthreads();
    bf16x8 qa = pun(*(const int4*)&sQ[hi * 256 + lo * 8]);
    bf16x8 qc = pun(*(const int4*)&sQ[(2 + hi) * 256 + lo * 8]);
    f32x16 c = {};
    c = mfma32(qa, k0, c);
    c = mfma32(qc, k1, c);
#pragma unroll
    for (int r = 0; r < 16; ++r) dl += __expf(c[r]);
    __syncthreads();
  }
  dl += __shfl_xor(dl, 32);
  if (hi == 0) dpart[(size_t)tpart * BS_ + (size_t)b * S_ + s0 + lo] = dl;
}

// K2b: reduce 4 t-part partials and invert.
__global__ __launch_bounds__(256) void dinv_kernel(const float* __restrict__ dpart,
                                                   float* __restrict__ dinv) {
  int i = blockIdx.x * 256 + threadIdx.x;
  float d = dpart[i] + dpart[BS_ + i] + dpart[2 * BS_ + i] + dpart[3 * BS_ + i];
  dinv[i] = 1.0f / d;
}

// ---------------------------------------------------------------------------
// vscale: vsT[b][h][s] = bf16(v[b][s][h] * dinv[b][s]), h padded to 32.
// ---------------------------------------------------------------------------
__global__ __launch_bounds__(256) void vscale_kernel(
    const float* __restrict__ vv, const float* __restrict__ dinv,
    ushort* __restrict__ vsT) {
  int gid = blockIdx.x * 256 + threadIdx.x;  // < 16*32*512
  int s4 = gid & 511;
  int h = (gid >> 9) & 31;
  int b = gid >> 14;
  int s0 = s4 * 4;
  ushort4 ov;
  if (h < H_) {
    const float* vp = vv + ((size_t)b * S_ + s0) * H_ + h;
    const float* dp = dinv + (size_t)b * S_ + s0;
    ov.x = f2bf(vp[0 * H_] * dp[0]);
    ov.y = f2bf(vp[1 * H_] * dp[1]);
    ov.z = f2bf(vp[2 * H_] * dp[2]);
    ov.w = f2bf(vp[3 * H_] * dp[3]);
  } else {
    ov.x = ov.y = ov.z = ov.w = 0;
  }
  *(ushort4*)&vsT[((size_t)b * 32 + h) * S_ + s0] = ov;
}

// ---------------------------------------------------------------------------
// Pass 2: h1[t,h] = sum_s exp(q_t.k_s) * vs[s,h]  (vs = v/d, pre-scaled).
// Swapped QK^T: C' = mfma(K,Q) -> P'[s][t]; P' -> PV A-operand in-register
// via cvt_pk_bf16 + permlane32_swap. grid (T/128, B, 4 s-parts).
// ---------------------------------------------------------------------------
__global__ __launch_bounds__(256) void attn_mfma(
    const ushort* __restrict__ qb, const ushort* __restrict__ kb,
    const ushort* __restrict__ vsT, ushort* __restrict__ h1p) {
  __shared__ __align__(16) ushort sK[4 * 32 * 8];  // [hslot][s][8]
  __shared__ __align__(16) ushort sV[4 * 32 * 8];  // [sslot][h][8]
  const int tid = threadIdx.x;
  const int lane = tid & 63;
  const int lo = lane & 31, hi = lane >> 5;
  const int w = tid >> 6;
  const int b = blockIdx.y;
  const int t0 = blockIdx.x * 128 + w * 32;
  const int spart = blockIdx.z;

  const ushort* qrow = qb + ((size_t)b * T_ + t0 + lo) * 32;
  bf16x8 q0 = pun(*(const int4*)(qrow + hi * 8));
  bf16x8 q1 = pun(*(const int4*)(qrow + 16 + hi * 8));

  f32x16 hacc = {};
  for (int sc = 0; sc < 16; ++sc) {
    const int sbase = spart * 512 + sc * 32;
    if (tid < 128) {
      int s = tid >> 2, j = tid & 3;
      *(int4*)&sK[j * 256 + s * 8] =
          *(const int4*)(kb + ((size_t)b * S_ + sbase + s) * 32 + j * 8);
    } else {
      int i2 = tid - 128;
      int h = i2 >> 2, q = i2 & 3;
      *(int4*)&sV[q * 256 + h * 8] =
          *(const int4*)(vsT + ((size_t)b * 32 + h) * S_ + sbase + q * 8);
    }
    __syncthreads();
    bf16x8 ka = pun(*(const int4*)&sK[hi * 256 + lo * 8]);
    bf16x8 kc = pun(*(const int4*)&sK[(2 + hi) * 256 + lo * 8]);
    bf16x8 va = pun(*(const int4*)&sV[hi * 256 + lo * 8]);
    bf16x8 vc = pun(*(const int4*)&sV[(2 + hi) * 256 + lo * 8]);
    f32x16 c = {};
    c = mfma32(ka, q0, c);
    c = mfma32(kc, q1, c);
    uint pk[8];
#pragma unroll
    for (int m = 0; m < 8; ++m) {
      float plo = __expf(c[2 * m]);
      float phi = __expf(c[2 * m + 1]);
      pk[m] = cvtpk(plo, phi);
    }
    asm("v_permlane32_swap_b32 %0, %1" : "+v"(pk[0]), "+v"(pk[2]));
    asm("v_permlane32_swap_b32 %0, %1" : "+v"(pk[1]), "+v"(pk[3]));
    asm("v_permlane32_swap_b32 %0, %1" : "+v"(pk[4]), "+v"(pk[6]));
    asm("v_permlane32_swap_b32 %0, %1" : "+v"(pk[5]), "+v"(pk[7]));
    int4 f0 = make_int4(pk[0], pk[1], pk[2], pk[3]);  // s 0..15 of chunk
    int4 f1 = make_int4(pk[4], pk[5], pk[6], pk[7]);  // s 16..31
    hacc = mfma32(pun(f0), va, hacc);
    hacc = mfma32(pun(f1), vc, hacc);
    __syncthreads();
  }
  ushort* o = h1p + (size_t)spart * QN32_ + (size_t)b * T_ * 32;
#pragma unroll
  for (int r = 0; r < 16; ++r) {
    int trow = t0 + (r & 3) + 8 * (r >> 2) + 4 * hi;
    o[(size_t)trow * 32 + lo] = f2bf(hacc[r]);
  }
}

// ---------------------------------------------------------------------------
// K4: out[r][d] = sum_h h1[r][h] * wh[h][d]; folds 4 bf16 s-part partials.
// ---------------------------------------------------------------------------
__global__ __launch_bounds__(256) void out_kernel(const ushort* __restrict__ h1p,
                                                  const float* __restrict__ wh,
                                                  float* __restrict__ out) {
  __shared__ __align__(16) float s_h1[16 * 24];
  const int tid = threadIdx.x;
  const long rbase = (long)blockIdx.x * 16;
  for (int i = tid; i < 16 * H_; i += 256) {
    int r = i / 24, h = i - r * 24;
    size_t off = (size_t)(rbase + r) * 32 + h;
    s_h1[i] = bf2f(h1p[off]) + bf2f(h1p[off + QN32_]) +
              bf2f(h1p[off + 2 * QN32_]) + bf2f(h1p[off + 3 * QN32_]);
  }
  __syncthreads();
  for (int c = 0; c < 4; ++c) {
    const int dd = c * 256 + tid;
    float wr[24];
#pragma unroll
    for (int h = 0; h < 24; ++h) wr[h] = wh[h * D_ + dd];
#pragma unroll 1
    for (int r = 0; r < 16; ++r) {
      float a = 0.f;
#pragma unroll
      for (int j = 0; j < 6; ++j) {
        float4 hv = *(const float4*)(s_h1 + r * 24 + 4 * j);
        a = fmaf(hv.x, wr[4 * j], a);
        a = fmaf(hv.y, wr[4 * j + 1], a);
        a = fmaf(hv.z, wr[4 * j + 2], a);
        a = fmaf(hv.w, wr[4 * j + 3], a);
      }
      out[(rbase + r) * D_ + dd] = a;
    }
  }
}

// ---------------------------------------------------------------------------
extern "C" void kernel_launch(void* const* d_in, const int* in_sizes, int n_in,
                              void* d_out, int out_size, void* d_ws,
                              size_t ws_size, hipStream_t stream) {
  const float* encoded = (const float*)d_in[0];
  const float* text = (const float*)d_in[1];
  const float* wq = (const float*)d_in[2];
  const float* wk = (const float*)d_in[3];
  const float* wv = (const float*)d_in[4];
  const float* wh = (const float*)d_in[5];
  float* out = (float*)d_out;

  // workspace layout: 17.6 MiB total (proven budget >= 22.6 MiB from R2)
  ushort* qb = (ushort*)d_ws;              // [B][T][32] bf16  (2 MiB)
  ushort* kbuf = qb + QN32_;               // [B][S][32] bf16  (2 MiB)
  float* vv = (float*)(kbuf + QN32_);      // [B][S][24] f32   (3 MiB)
  float* dpart = vv + (size_t)BS_ * H_;    // [4][B*S] f32     (0.5 MiB)
  float* dinv = dpart + 4 * BS_;           // [B*S] f32        (0.13 MiB)
  ushort* vsT = (ushort*)(dinv + BS_);     // [B][32][S] bf16  (2 MiB)
  ushort* h1p = vsT + (size_t)B_ * 32 * S_;// [4][B][T][32] bf16 (8 MiB)

  proj_mfma<1><<<NROW_ / 128, 256, 0, stream>>>(text, wq, nullptr, qb, nullptr);
  proj_mfma<2><<<NROW_ / 128, 256, 0, stream>>>(encoded, wk, wv, kbuf, vv);
  colsum_mfma<<<dim3(S_ / 128, B_, 4), 256, 0, stream>>>(qb, kbuf, dpart);
  dinv_kernel<<<BS_ / 256, 256, 0, stream>>>(dpart, dinv);
  vscale_kernel<<<(B_ * 32 * (S_ / 4)) / 256, 256, 0, stream>>>(vv, dinv, vsT);
  attn_mfma<<<dim3(T_ / 128, B_, 4), 256, 0, stream>>>(qb, kbuf, vsT, h1p);
  out_kernel<<<NROW_ / 16, 256, 0, stream>>>(h1p, wh, out);
}

// Round 7
// 161.602 us; speedup vs baseline: 3.3565x; 1.1546x over previous
//
#include <hip/hip_runtime.h>
#include <hip/hip_bf16.h>

// Problem: B=16, T=S=2048, D=1024, H=24
#define B_ 16
#define T_ 2048
#define S_ 2048
#define D_ 1024
#define H_ 24
#define NROW_ (B_ * T_)            // 32768 rows
#define BS_ (B_ * S_)              // 32768
#define QN32_ ((size_t)NROW_ * 32) // padded projection / h1-part elements

typedef float f32x16 __attribute__((ext_vector_type(16)));
typedef __bf16 bf16x8 __attribute__((ext_vector_type(8)));

union B8u { int4 i; bf16x8 b; };
__device__ inline bf16x8 pun(int4 v) { B8u u; u.i = v; return u.b; }

__device__ inline ushort f2bf(float f) {  // RNE fp32->bf16
  uint u = __float_as_uint(f);
  u += 0x7fffu + ((u >> 16) & 1u);
  return (ushort)(u >> 16);
}
__device__ inline float bf2f(ushort u) { return __uint_as_float(((uint)u) << 16); }

__device__ inline f32x16 mfma32(bf16x8 a, bf16x8 b, f32x16 c) {
  return __builtin_amdgcn_mfma_f32_32x32x16_bf16(a, b, c, 0, 0, 0);
}

__device__ inline uint cvtpk(float a, float b) {
  uint r;
  asm("v_cvt_pk_bf16_f32 %0, %1, %2" : "=v"(r) : "v"(a), "v"(b));
  return r;
}

// ---------------------------------------------------------------------------
// prep_w: pack wq,wk,wv -> global fragment-order bf16 wpk[3][128][24][8].
// Entry (which,k8g,n) holds w[(k8g*8+j)][n], j=0..7. 144 KB total, L2-hot.
// ---------------------------------------------------------------------------
__global__ __launch_bounds__(256) void prep_w(
    const float* __restrict__ wq, const float* __restrict__ wk,
    const float* __restrict__ wv, ushort* __restrict__ wpk) {
  int i = blockIdx.x * 256 + threadIdx.x;  // < 3*128*24 = 9216
  if (i >= 3 * 128 * H_) return;
  int which = i / (128 * H_);
  int rem = i - which * 128 * H_;
  int k8g = rem / H_, n = rem - k8g * H_;
  const float* w = (which == 0) ? wq : (which == 1) ? wk : wv;
  ushort t[8];
#pragma unroll
  for (int j = 0; j < 8; ++j) t[j] = f2bf(w[(k8g * 8 + j) * H_ + n]);
  *(int4*)&wpk[(size_t)i * 8] = *(const int4*)t;
}

// ---------------------------------------------------------------------------
// proj_unified (R7): both projections in one kernel.
//   bid < 1024:  text -> qb (bf16 [row][32], pad 0)
//   bid >= 1024: encoded -> kbuf (bf16 [row][32], pad 0) + vv (f32 [row][24])
// Design: 32 rows/block, K-split x4 (wave w owns K in [w*256,(w+1)*256)).
// Per 64-col window: wave loads 8 coalesced 256B runs, cvt->bf16, ds_write
// into WAVE-PRIVATE sA[w][k8][row^k8][8] (XOR spreads write banks; read
// [k8=2cl+hi][lo^k8] b128 stays conflict-free). NO barriers in K-loop.
// B-frags read straight from global wpk (L2-hot 16B/lane). Epilogue:
// cross-wave partial reduce through padded LDS (stride 17 -> conflict-free).
// LDS 33.4 KiB -> ~4 blocks/CU -> ~4 waves/SIMD (vs R6's 1): HBM-latency
// hidden by TLP.
// ---------------------------------------------------------------------------
__global__ __launch_bounds__(256) void proj_unified(
    const float* __restrict__ text, const float* __restrict__ encoded,
    const ushort* __restrict__ wpk, ushort* __restrict__ qb,
    ushort* __restrict__ kbuf, float* __restrict__ vv) {
  __shared__ __align__(16) ushort sA[4][8][32][8];  // 16 KiB, per-wave slabs
  __shared__ __align__(16) float sRed[4][1088];     // 17 KiB reduce scratch

  const int tid = threadIdx.x;
  const int lane = tid & 63, lo = lane & 31, hi = lane >> 5, w = tid >> 6;
  const bool kvmode = (blockIdx.x >= 1024);
  const int bid = kvmode ? (blockIdx.x - 1024) : blockIdx.x;
  const float* in = kvmode ? encoded : text;
  const ushort* wp1 = wpk + (size_t)(kvmode ? 1 : 0) * 128 * H_ * 8;
  const ushort* wp2 = wpk + (size_t)2 * 128 * H_ * 8;
  const long rowbase = (long)bid * 32;
  const int ne = (lo < H_) ? lo : 0;  // dup col for pad lanes (never written)

  const float* base = in + rowbase * D_ + w * 256;

  f32x16 acc = {};
  f32x16 acc2 = {};

#pragma unroll
  for (int win = 0; win < 4; ++win) {
    // load 32 rows x 64 cols fp32, coalesced 256B runs (4 rows/instr)
    float4 fv[8];
#pragma unroll
    for (int i = 0; i < 8; ++i) {
      int g = lane + 64 * i, row = g >> 4, f4 = g & 15;
      fv[i] = *(const float4*)(base + row * D_ + win * 64 + f4 * 4);
    }
    // cvt + wave-private ds_write (XOR-swizzled rows)
#pragma unroll
    for (int i = 0; i < 8; ++i) {
      int g = lane + 64 * i, row = g >> 4, f4 = g & 15;
      int k8 = f4 >> 1, par = f4 & 1;
      uint p0 = cvtpk(fv[i].x, fv[i].y), p1 = cvtpk(fv[i].z, fv[i].w);
      *(uint2*)&sA[w][k8][row ^ k8][par * 4] = make_uint2(p0, p1);
    }
    // MFMA over this window's 8 k-octets (wave-local; compiler waits lgkm)
#pragma unroll
    for (int cl = 0; cl < 4; ++cl) {
      const int k8 = 2 * cl + hi;
      bf16x8 a = pun(*(const int4*)&sA[w][k8][lo ^ k8][0]);
      const int k8g = w * 32 + win * 8 + k8;
      bf16x8 b1 = pun(*(const int4*)&wp1[(size_t)(k8g * H_ + ne) * 8]);
      acc = mfma32(a, b1, acc);
      if (kvmode) {
        bf16x8 b2 = pun(*(const int4*)&wp2[(size_t)(k8g * H_ + ne) * 8]);
        acc2 = mfma32(a, b2, acc2);
      }
    }
  }

  // ---- cross-wave K-partial reduce (padded stride 17: conflict-free) ----
#pragma unroll
  for (int r = 0; r < 16; ++r) sRed[w][lane * 17 + r] = acc[r];
  __syncthreads();
  {
    const int qd = tid >> 6, l = tid & 63, lo2 = l & 31, hi2 = l >> 5;
    ushort* o1 = (kvmode ? kbuf : qb);
#pragma unroll
    for (int rr = 0; rr < 4; ++rr) {
      const int r = qd * 4 + rr;
      float s = sRed[0][l * 17 + r] + sRed[1][l * 17 + r] +
                sRed[2][l * 17 + r] + sRed[3][l * 17 + r];
      const int mrow = rr + 8 * qd + 4 * hi2;
      o1[(size_t)(rowbase + mrow) * 32 + lo2] = (lo2 < H_) ? f2bf(s) : (ushort)0;
    }
  }
  if (kvmode) {
    __syncthreads();  // WAR on sRed
#pragma unroll
    for (int r = 0; r < 16; ++r) sRed[w][lane * 17 + r] = acc2[r];
    __syncthreads();
    const int qd = tid >> 6, l = tid & 63, lo2 = l & 31, hi2 = l >> 5;
    if (lo2 < H_) {
#pragma unroll
      for (int rr = 0; rr < 4; ++rr) {
        const int r = qd * 4 + rr;
        float s = sRed[0][l * 17 + r] + sRed[1][l * 17 + r] +
                  sRed[2][l * 17 + r] + sRed[3][l * 17 + r];
        const int mrow = rr + 8 * qd + 4 * hi2;
        vv[(size_t)(rowbase + mrow) * H_ + lo2] = s;
      }
    }
  }
}

// ---------------------------------------------------------------------------
// Pass 1: d[b,s] = sum_t exp(q_t . k_s) via un-swapped MFMA.
// C[r=t][c=s]: lane owns one s-column (c = lane&31); sum 16 regs + xor32.
// grid (S/128, B, 4 t-parts); block 256 = 4 waves (one 32-s chunk each).
// ---------------------------------------------------------------------------
__global__ __launch_bounds__(256) void colsum_mfma(
    const ushort* __restrict__ qb, const ushort* __restrict__ kb,
    float* __restrict__ dpart) {
  __shared__ __align__(16) ushort sQ[4 * 32 * 8];  // [hslot][t][8]
  const int tid = threadIdx.x;
  const int lane = tid & 63;
  const int lo = lane & 31, hi = lane >> 5;
  const int w = tid >> 6;
  const int b = blockIdx.y;
  const int s0 = blockIdx.x * 128 + w * 32;
  const int tpart = blockIdx.z;

  const ushort* krow = kb + ((size_t)b * S_ + s0 + lo) * 32;
  bf16x8 k0 = pun(*(const int4*)(krow + hi * 8));
  bf16x8 k1 = pun(*(const int4*)(krow + 16 + hi * 8));

  float dl = 0.f;
  for (int tc = 0; tc < 16; ++tc) {
    const int tbase = tpart * 512 + tc * 32;
    if (tid < 128) {
      int t = tid >> 2, j = tid & 3;
      *(int4*)&sQ[j * 256 + t * 8] =
          *(const int4*)(qb + ((size_t)b * T_ + tbase + t) * 32 + j * 8);
    }
    __syncthreads();
    bf16x8 qa = pun(*(const int4*)&sQ[hi * 256 + lo * 8]);
    bf16x8 qc = pun(*(const int4*)&sQ[(2 + hi) * 256 + lo * 8]);
    f32x16 c = {};
    c = mfma32(qa, k0, c);
    c = mfma32(qc, k1, c);
#pragma unroll
    for (int r = 0; r < 16; ++r) dl += __expf(c[r]);
    __syncthreads();
  }
  dl += __shfl_xor(dl, 32);
  if (hi == 0) dpart[(size_t)tpart * BS_ + (size_t)b * S_ + s0 + lo] = dl;
}

// ---------------------------------------------------------------------------
// vscale (R7: dpart reduce folded in): vsT[b][h][s] = bf16(v * 1/d), h pad 32.
// ---------------------------------------------------------------------------
__global__ __launch_bounds__(256) void vscale_kernel(
    const float* __restrict__ vv, const float* __restrict__ dpart,
    ushort* __restrict__ vsT) {
  int gid = blockIdx.x * 256 + threadIdx.x;  // < 16*32*512
  int s4 = gid & 511;
  int h = (gid >> 9) & 31;
  int b = gid >> 14;
  int s0 = s4 * 4;
  ushort4 ov;
  if (h < H_) {
    const float* vp = vv + ((size_t)b * S_ + s0) * H_ + h;
    const float* dp = dpart + (size_t)b * S_ + s0;
    float dv[4];
#pragma unroll
    for (int i = 0; i < 4; ++i) {
      float d = dp[i] + dp[BS_ + i] + dp[2 * BS_ + i] + dp[3 * BS_ + i];
      dv[i] = 1.0f / d;
    }
    ov.x = f2bf(vp[0 * H_] * dv[0]);
    ov.y = f2bf(vp[1 * H_] * dv[1]);
    ov.z = f2bf(vp[2 * H_] * dv[2]);
    ov.w = f2bf(vp[3 * H_] * dv[3]);
  } else {
    ov.x = ov.y = ov.z = ov.w = 0;
  }
  *(ushort4*)&vsT[((size_t)b * 32 + h) * S_ + s0] = ov;
}

// ---------------------------------------------------------------------------
// Pass 2: h1[t,h] = sum_s exp(q_t.k_s) * vs[s,h]  (vs = v/d, pre-scaled).
// Swapped QK^T: C' = mfma(K,Q) -> P'[s][t]; P' -> PV A-operand in-register
// via cvt_pk_bf16 + permlane32_swap. grid (T/128, B, 4 s-parts).
// ---------------------------------------------------------------------------
__global__ __launch_bounds__(256) void attn_mfma(
    const ushort* __restrict__ qb, const ushort* __restrict__ kb,
    const ushort* __restrict__ vsT, ushort* __restrict__ h1p) {
  __shared__ __align__(16) ushort sK[4 * 32 * 8];  // [hslot][s][8]
  __shared__ __align__(16) ushort sV[4 * 32 * 8];  // [sslot][h][8]
  const int tid = threadIdx.x;
  const int lane = tid & 63;
  const int lo = lane & 31, hi = lane >> 5;
  const int w = tid >> 6;
  const int b = blockIdx.y;
  const int t0 = blockIdx.x * 128 + w * 32;
  const int spart = blockIdx.z;

  const ushort* qrow = qb + ((size_t)b * T_ + t0 + lo) * 32;
  bf16x8 q0 = pun(*(const int4*)(qrow + hi * 8));
  bf16x8 q1 = pun(*(const int4*)(qrow + 16 + hi * 8));

  f32x16 hacc = {};
  for (int sc = 0; sc < 16; ++sc) {
    const int sbase = spart * 512 + sc * 32;
    if (tid < 128) {
      int s = tid >> 2, j = tid & 3;
      *(int4*)&sK[j * 256 + s * 8] =
          *(const int4*)(kb + ((size_t)b * S_ + sbase + s) * 32 + j * 8);
    } else {
      int i2 = tid - 128;
      int h = i2 >> 2, q = i2 & 3;
      *(int4*)&sV[q * 256 + h * 8] =
          *(const int4*)(vsT + ((size_t)b * 32 + h) * S_ + sbase + q * 8);
    }
    __syncthreads();
    bf16x8 ka = pun(*(const int4*)&sK[hi * 256 + lo * 8]);
    bf16x8 kc = pun(*(const int4*)&sK[(2 + hi) * 256 + lo * 8]);
    bf16x8 va = pun(*(const int4*)&sV[hi * 256 + lo * 8]);
    bf16x8 vc = pun(*(const int4*)&sV[(2 + hi) * 256 + lo * 8]);
    f32x16 c = {};
    c = mfma32(ka, q0, c);
    c = mfma32(kc, q1, c);
    uint pk[8];
#pragma unroll
    for (int m = 0; m < 8; ++m) {
      float plo = __expf(c[2 * m]);
      float phi = __expf(c[2 * m + 1]);
      pk[m] = cvtpk(plo, phi);
    }
    asm("v_permlane32_swap_b32 %0, %1" : "+v"(pk[0]), "+v"(pk[2]));
    asm("v_permlane32_swap_b32 %0, %1" : "+v"(pk[1]), "+v"(pk[3]));
    asm("v_permlane32_swap_b32 %0, %1" : "+v"(pk[4]), "+v"(pk[6]));
    asm("v_permlane32_swap_b32 %0, %1" : "+v"(pk[5]), "+v"(pk[7]));
    int4 f0 = make_int4(pk[0], pk[1], pk[2], pk[3]);  // s 0..15 of chunk
    int4 f1 = make_int4(pk[4], pk[5], pk[6], pk[7]);  // s 16..31
    hacc = mfma32(pun(f0), va, hacc);
    hacc = mfma32(pun(f1), vc, hacc);
    __syncthreads();
  }
  ushort* o = h1p + (size_t)spart * QN32_ + (size_t)b * T_ * 32;
#pragma unroll
  for (int r = 0; r < 16; ++r) {
    int trow = t0 + (r & 3) + 8 * (r >> 2) + 4 * hi;
    o[(size_t)trow * 32 + lo] = f2bf(hacc[r]);
  }
}

// ---------------------------------------------------------------------------
// K4: out[r][d] = sum_h h1[r][h] * wh[h][d]; folds 4 bf16 s-part partials.
// R7: h1 staging vectorized (int4; 48 threads x 4 partial loads).
// ---------------------------------------------------------------------------
__global__ __launch_bounds__(256) void out_kernel(const ushort* __restrict__ h1p,
                                                  const float* __restrict__ wh,
                                                  float* __restrict__ out) {
  __shared__ __align__(16) float s_h1[16 * 24];
  const int tid = threadIdx.x;
  const long rbase = (long)blockIdx.x * 16;
  if (tid < 48) {
    const int r = tid / 3, c8 = tid - 3 * r;  // cols [8c8, 8c8+8) < 24
    float s[8] = {0.f, 0.f, 0.f, 0.f, 0.f, 0.f, 0.f, 0.f};
#pragma unroll
    for (int part = 0; part < 4; ++part) {
      int4 v = *(const int4*)&h1p[(size_t)part * QN32_ +
                                  (size_t)(rbase + r) * 32 + c8 * 8];
      const ushort* u = (const ushort*)&v;
#pragma unroll
      for (int j = 0; j < 8; ++j) s[j] += bf2f(u[j]);
    }
#pragma unroll
    for (int j = 0; j < 8; ++j) s_h1[r * 24 + c8 * 8 + j] = s[j];
  }
  __syncthreads();
  for (int c = 0; c < 4; ++c) {
    const int dd = c * 256 + tid;
    float wr[24];
#pragma unroll
    for (int h = 0; h < 24; ++h) wr[h] = wh[h * D_ + dd];
#pragma unroll 1
    for (int r = 0; r < 16; ++r) {
      float a = 0.f;
#pragma unroll
      for (int j = 0; j < 6; ++j) {
        float4 hv = *(const float4*)(s_h1 + r * 24 + 4 * j);
        a = fmaf(hv.x, wr[4 * j], a);
        a = fmaf(hv.y, wr[4 * j + 1], a);
        a = fmaf(hv.z, wr[4 * j + 2], a);
        a = fmaf(hv.w, wr[4 * j + 3], a);
      }
      out[(rbase + r) * D_ + dd] = a;
    }
  }
}

// ---------------------------------------------------------------------------
extern "C" void kernel_launch(void* const* d_in, const int* in_sizes, int n_in,
                              void* d_out, int out_size, void* d_ws,
                              size_t ws_size, hipStream_t stream) {
  const float* encoded = (const float*)d_in[0];
  const float* text = (const float*)d_in[1];
  const float* wq = (const float*)d_in[2];
  const float* wk = (const float*)d_in[3];
  const float* wv = (const float*)d_in[4];
  const float* wh = (const float*)d_in[5];
  float* out = (float*)d_out;

  // workspace layout: ~17.7 MiB total
  ushort* qb = (ushort*)d_ws;               // [B][T][32] bf16  (2 MiB)
  ushort* kbuf = qb + QN32_;                // [B][S][32] bf16  (2 MiB)
  float* vv = (float*)(kbuf + QN32_);       // [B][S][24] f32   (3 MiB)
  float* dpart = vv + (size_t)BS_ * H_;     // [4][B*S] f32     (0.5 MiB)
  ushort* vsT = (ushort*)(dpart + 4 * BS_); // [B][32][S] bf16  (2 MiB)
  ushort* h1p = vsT + (size_t)B_ * 32 * S_; // [4][B][T][32] bf16 (8 MiB)
  ushort* wpk = h1p + 4 * QN32_;            // [3][128][24][8] bf16 (144 KiB)

  prep_w<<<36, 256, 0, stream>>>(wq, wk, wv, wpk);
  proj_unified<<<2048, 256, 0, stream>>>(text, encoded, wpk, qb, kbuf, vv);
  colsum_mfma<<<dim3(S_ / 128, B_, 4), 256, 0, stream>>>(qb, kbuf, dpart);
  vscale_kernel<<<(B_ * 32 * (S_ / 4)) / 256, 256, 0, stream>>>(vv, dpart, vsT);
  attn_mfma<<<dim3(T_ / 128, B_, 4), 256, 0, stream>>>(qb, kbuf, vsT, h1p);
  out_kernel<<<NROW_ / 16, 256, 0, stream>>>(h1p, wh, out);
}

// Round 8
// 156.544 us; speedup vs baseline: 3.4649x; 1.0323x over previous
//
#include <hip/hip_runtime.h>
#include <hip/hip_bf16.h>

// Problem: B=16, T=S=2048, D=1024, H=24
#define B_ 16
#define T_ 2048
#define S_ 2048
#define D_ 1024
#define H_ 24
#define NROW_ (B_ * T_)            // 32768 rows
#define BS_ (B_ * S_)              // 32768
#define QN32_ ((size_t)NROW_ * 32) // padded projection / h1-part elements

typedef float f32x16 __attribute__((ext_vector_type(16)));
typedef __bf16 bf16x8 __attribute__((ext_vector_type(8)));

union B8u { int4 i; bf16x8 b; };
__device__ inline bf16x8 pun(int4 v) { B8u u; u.i = v; return u.b; }

__device__ inline ushort f2bf(float f) {  // RNE fp32->bf16
  uint u = __float_as_uint(f);
  u += 0x7fffu + ((u >> 16) & 1u);
  return (ushort)(u >> 16);
}
__device__ inline float bf2f(ushort u) { return __uint_as_float(((uint)u) << 16); }

__device__ inline f32x16 mfma32(bf16x8 a, bf16x8 b, f32x16 c) {
  return __builtin_amdgcn_mfma_f32_32x32x16_bf16(a, b, c, 0, 0, 0);
}

__device__ inline uint cvtpk(float a, float b) {
  uint r;
  asm("v_cvt_pk_bf16_f32 %0, %1, %2" : "=v"(r) : "v"(a), "v"(b));
  return r;
}

#define AS1C(p) ((const __attribute__((address_space(1))) void*)((const void*)(p)))
#define AS3(p) ((__attribute__((address_space(3))) void*)((void*)(p)))

// ---------------------------------------------------------------------------
// prep_w: pack wq,wk,wv -> global fragment-order bf16 wpk[3][128][24][8].
// ---------------------------------------------------------------------------
__global__ __launch_bounds__(256) void prep_w(
    const float* __restrict__ wq, const float* __restrict__ wk,
    const float* __restrict__ wv, ushort* __restrict__ wpk) {
  int i = blockIdx.x * 256 + threadIdx.x;  // < 3*128*24 = 9216
  if (i >= 3 * 128 * H_) return;
  int which = i / (128 * H_);
  int rem = i - which * 128 * H_;
  int k8g = rem / H_, n = rem - k8g * H_;
  const float* w = (which == 0) ? wq : (which == 1) ? wk : wv;
  ushort t[8];
#pragma unroll
  for (int j = 0; j < 8; ++j) t[j] = f2bf(w[(k8g * 8 + j) * H_ + n]);
  *(int4*)&wpk[(size_t)i * 8] = *(const int4*)t;
}

// ---------------------------------------------------------------------------
// proj_unified (R8): fire-and-forget staging via global_load_lds (fp32,
// width=16) + counted vmcnt(8) -> staging never drains to 0 (R7 stalled in
// vmcnt(0) every window: 2.55 TB/s effective, all pipes <5%).
//  - K-split x4: wave w owns cols [w*256,(w+1)*256) of its block's 32 rows.
//  - ALL B-fragments preloaded to VGPRs before the loop (16 q / 32 kv) so
//    the K-loop's ONLY vmem traffic is global_load_lds (clean vmcnt count).
//  - Both-sides swizzle (gload_lds writes linearly): source granule index
//    c16 ^= (row&7)<<1 (pair-preserving), same XOR on ds_read -> coalesced
//    HBM 16B granules, <=8-way LDS read (harmless, LDS has headroom).
//  - Wave-private dbuf slabs (2x8KB/wave), NO barriers in K-loop.
//  - sRed reduce scratch aliased into sA after a barrier. LDS 64KB -> 2
//    blocks/CU.
//   bid < 1024:  text -> qb (bf16 [row][32], pad 0)
//   bid >= 1024: encoded -> kbuf + vv (f32 [row][24])
// ---------------------------------------------------------------------------
__global__ __launch_bounds__(256, 2) void proj_unified(
    const float* __restrict__ text, const float* __restrict__ encoded,
    const ushort* __restrict__ wpk, ushort* __restrict__ qb,
    ushort* __restrict__ kbuf, float* __restrict__ vv) {
  __shared__ __align__(16) float sA[4][2][2048];  // 64 KiB: [wave][buf][32r*64c]

  const int tid = threadIdx.x;
  const int lane = tid & 63, lo = lane & 31, hi = lane >> 5, w = tid >> 6;
  const bool kvmode = (blockIdx.x >= 1024);
  const int bid = kvmode ? (blockIdx.x - 1024) : blockIdx.x;
  const float* in = kvmode ? encoded : text;
  const ushort* wp1 = wpk + (size_t)(kvmode ? 1 : 0) * 128 * H_ * 8;
  const ushort* wp2 = wpk + (size_t)2 * 128 * H_ * 8;
  const long rowbase = (long)bid * 32;
  const int ne = (lo < H_) ? lo : 0;  // dup col for pad lanes (never stored)

  // ---- preload ALL B-fragments for this wave's K-quarter into VGPRs ----
  int4 bfr1[16], bfr2[16];
#pragma unroll
  for (int win = 0; win < 4; ++win) {
#pragma unroll
    for (int cl = 0; cl < 4; ++cl) {
      const int k8g = w * 32 + win * 8 + 2 * cl + hi;
      bfr1[win * 4 + cl] = *(const int4*)&wp1[(size_t)(k8g * H_ + ne) * 8];
      if (kvmode)
        bfr2[win * 4 + cl] = *(const int4*)&wp2[(size_t)(k8g * H_ + ne) * 8];
    }
  }

  // per-lane fixed staging geometry: instr i covers rows 4i..4i+3
  const int srow = lane >> 4;          // row-within-quad  (0..3)
  const int c16l = lane & 15;          // lds granule slot (0..15)
  const float* gbase = in + rowbase * D_ + w * 256;

  f32x16 acc = {};
  f32x16 acc2 = {};

#define STAGE(win_, buf_)                                                     \
  {                                                                           \
    _Pragma("unroll") for (int i = 0; i < 8; ++i) {                           \
      const int row = i * 4 + srow;                                           \
      const int c16s = c16l ^ ((row & 7) << 1); /* source-side swizzle */     \
      const float* g = gbase + (size_t)row * D_ + (win_)*64 + c16s * 4;       \
      __builtin_amdgcn_global_load_lds(AS1C(g), AS3(&sA[w][buf_][i * 256]),   \
                                       16, 0, 0);                             \
    }                                                                         \
  }

  STAGE(0, 0);
#pragma unroll
  for (int win = 0; win < 4; ++win) {
    const int buf = win & 1;
    __builtin_amdgcn_sched_barrier(0);
    if (win < 3) {
      if (win == 0) STAGE(1, 1);
      if (win == 1) STAGE(2, 0);
      if (win == 2) STAGE(3, 1);
      asm volatile("s_waitcnt vmcnt(8)" ::: "memory");
    } else {
      asm volatile("s_waitcnt vmcnt(0)" ::: "memory");
    }
    __builtin_amdgcn_sched_barrier(0);
#pragma unroll
    for (int cl = 0; cl < 4; ++cl) {
      const int k8 = 2 * cl + hi;
      const int c16 = (2 * k8) ^ ((lo & 7) << 1);  // read-side swizzle
      float4 ga = *(const float4*)&sA[w][buf][lo * 64 + c16 * 4];
      float4 gb = *(const float4*)&sA[w][buf][lo * 64 + c16 * 4 + 4];
      uint p0 = cvtpk(ga.x, ga.y), p1 = cvtpk(ga.z, ga.w);
      uint p2 = cvtpk(gb.x, gb.y), p3 = cvtpk(gb.z, gb.w);
      bf16x8 a = pun(make_int4(p0, p1, p2, p3));
      acc = mfma32(a, pun(bfr1[win * 4 + cl]), acc);
      if (kvmode) acc2 = mfma32(a, pun(bfr2[win * 4 + cl]), acc2);
    }
  }
#undef STAGE

  // ---- cross-wave K-partial reduce (sRed aliased into sA) ----
  float* sR = (float*)sA;  // [4][1088], padded stride 17
  __syncthreads();         // all waves done reading their slabs
#pragma unroll
  for (int r = 0; r < 16; ++r) sR[w * 1088 + lane * 17 + r] = acc[r];
  __syncthreads();
  {
    const int qd = tid >> 6, l = tid & 63, lo2 = l & 31, hi2 = l >> 5;
    ushort* o1 = (kvmode ? kbuf : qb);
#pragma unroll
    for (int rr = 0; rr < 4; ++rr) {
      const int r = qd * 4 + rr;
      float s = sR[0 * 1088 + l * 17 + r] + sR[1 * 1088 + l * 17 + r] +
                sR[2 * 1088 + l * 17 + r] + sR[3 * 1088 + l * 17 + r];
      const int mrow = rr + 8 * qd + 4 * hi2;
      o1[(size_t)(rowbase + mrow) * 32 + lo2] = (lo2 < H_) ? f2bf(s) : (ushort)0;
    }
  }
  if (kvmode) {
    __syncthreads();  // WAR on sR
#pragma unroll
    for (int r = 0; r < 16; ++r) sR[w * 1088 + lane * 17 + r] = acc2[r];
    __syncthreads();
    const int qd = tid >> 6, l = tid & 63, lo2 = l & 31, hi2 = l >> 5;
    if (lo2 < H_) {
#pragma unroll
      for (int rr = 0; rr < 4; ++rr) {
        const int r = qd * 4 + rr;
        float s = sR[0 * 1088 + l * 17 + r] + sR[1 * 1088 + l * 17 + r] +
                  sR[2 * 1088 + l * 17 + r] + sR[3 * 1088 + l * 17 + r];
        const int mrow = rr + 8 * qd + 4 * hi2;
        vv[(size_t)(rowbase + mrow) * H_ + lo2] = s;
      }
    }
  }
}

// ---------------------------------------------------------------------------
// Pass 1: d[b,s] = sum_t exp(q_t . k_s) via un-swapped MFMA.
// ---------------------------------------------------------------------------
__global__ __launch_bounds__(256) void colsum_mfma(
    const ushort* __restrict__ qb, const ushort* __restrict__ kb,
    float* __restrict__ dpart) {
  __shared__ __align__(16) ushort sQ[4 * 32 * 8];  // [hslot][t][8]
  const int tid = threadIdx.x;
  const int lane = tid & 63;
  const int lo = lane & 31, hi = lane >> 5;
  const int w = tid >> 6;
  const int b = blockIdx.y;
  const int s0 = blockIdx.x * 128 + w * 32;
  const int tpart = blockIdx.z;

  const ushort* krow = kb + ((size_t)b * S_ + s0 + lo) * 32;
  bf16x8 k0 = pun(*(const int4*)(krow + hi * 8));
  bf16x8 k1 = pun(*(const int4*)(krow + 16 + hi * 8));

  float dl = 0.f;
  for (int tc = 0; tc < 16; ++tc) {
    const int tbase = tpart * 512 + tc * 32;
    if (tid < 128) {
      int t = tid >> 2, j = tid & 3;
      *(int4*)&sQ[j * 256 + t * 8] =
          *(const int4*)(qb + ((size_t)b * T_ + tbase + t) * 32 + j * 8);
    }
    __syncthreads();
    bf16x8 qa = pun(*(const int4*)&sQ[hi * 256 + lo * 8]);
    bf16x8 qc = pun(*(const int4*)&sQ[(2 + hi) * 256 + lo * 8]);
    f32x16 c = {};
    c = mfma32(qa, k0, c);
    c = mfma32(qc, k1, c);
#pragma unroll
    for (int r = 0; r < 16; ++r) dl += __expf(c[r]);
    __syncthreads();
  }
  dl += __shfl_xor(dl, 32);
  if (hi == 0) dpart[(size_t)tpart * BS_ + (size_t)b * S_ + s0 + lo] = dl;
}

// ---------------------------------------------------------------------------
// vscale (dpart reduce folded in): vsT[b][h][s] = bf16(v * 1/d), h pad 32.
// ---------------------------------------------------------------------------
__global__ __launch_bounds__(256) void vscale_kernel(
    const float* __restrict__ vv, const float* __restrict__ dpart,
    ushort* __restrict__ vsT) {
  int gid = blockIdx.x * 256 + threadIdx.x;  // < 16*32*512
  int s4 = gid & 511;
  int h = (gid >> 9) & 31;
  int b = gid >> 14;
  int s0 = s4 * 4;
  ushort4 ov;
  if (h < H_) {
    const float* vp = vv + ((size_t)b * S_ + s0) * H_ + h;
    const float* dp = dpart + (size_t)b * S_ + s0;
    float dv[4];
#pragma unroll
    for (int i = 0; i < 4; ++i) {
      float d = dp[i] + dp[BS_ + i] + dp[2 * BS_ + i] + dp[3 * BS_ + i];
      dv[i] = 1.0f / d;
    }
    ov.x = f2bf(vp[0 * H_] * dv[0]);
    ov.y = f2bf(vp[1 * H_] * dv[1]);
    ov.z = f2bf(vp[2 * H_] * dv[2]);
    ov.w = f2bf(vp[3 * H_] * dv[3]);
  } else {
    ov.x = ov.y = ov.z = ov.w = 0;
  }
  *(ushort4*)&vsT[((size_t)b * 32 + h) * S_ + s0] = ov;
}

// ---------------------------------------------------------------------------
// Pass 2: h1[t,h] = sum_s exp(q_t.k_s) * vs[s,h]  (vs = v/d, pre-scaled).
// ---------------------------------------------------------------------------
__global__ __launch_bounds__(256) void attn_mfma(
    const ushort* __restrict__ qb, const ushort* __restrict__ kb,
    const ushort* __restrict__ vsT, ushort* __restrict__ h1p) {
  __shared__ __align__(16) ushort sK[4 * 32 * 8];  // [hslot][s][8]
  __shared__ __align__(16) ushort sV[4 * 32 * 8];  // [sslot][h][8]
  const int tid = threadIdx.x;
  const int lane = tid & 63;
  const int lo = lane & 31, hi = lane >> 5;
  const int w = tid >> 6;
  const int b = blockIdx.y;
  const int t0 = blockIdx.x * 128 + w * 32;
  const int spart = blockIdx.z;

  const ushort* qrow = qb + ((size_t)b * T_ + t0 + lo) * 32;
  bf16x8 q0 = pun(*(const int4*)(qrow + hi * 8));
  bf16x8 q1 = pun(*(const int4*)(qrow + 16 + hi * 8));

  f32x16 hacc = {};
  for (int sc = 0; sc < 16; ++sc) {
    const int sbase = spart * 512 + sc * 32;
    if (tid < 128) {
      int s = tid >> 2, j = tid & 3;
      *(int4*)&sK[j * 256 + s * 8] =
          *(const int4*)(kb + ((size_t)b * S_ + sbase + s) * 32 + j * 8);
    } else {
      int i2 = tid - 128;
      int h = i2 >> 2, q = i2 & 3;
      *(int4*)&sV[q * 256 + h * 8] =
          *(const int4*)(vsT + ((size_t)b * 32 + h) * S_ + sbase + q * 8);
    }
    __syncthreads();
    bf16x8 ka = pun(*(const int4*)&sK[hi * 256 + lo * 8]);
    bf16x8 kc = pun(*(const int4*)&sK[(2 + hi) * 256 + lo * 8]);
    bf16x8 va = pun(*(const int4*)&sV[hi * 256 + lo * 8]);
    bf16x8 vc = pun(*(const int4*)&sV[(2 + hi) * 256 + lo * 8]);
    f32x16 c = {};
    c = mfma32(ka, q0, c);
    c = mfma32(kc, q1, c);
    uint pk[8];
#pragma unroll
    for (int m = 0; m < 8; ++m) {
      float plo = __expf(c[2 * m]);
      float phi = __expf(c[2 * m + 1]);
      pk[m] = cvtpk(plo, phi);
    }
    asm("v_permlane32_swap_b32 %0, %1" : "+v"(pk[0]), "+v"(pk[2]));
    asm("v_permlane32_swap_b32 %0, %1" : "+v"(pk[1]), "+v"(pk[3]));
    asm("v_permlane32_swap_b32 %0, %1" : "+v"(pk[4]), "+v"(pk[6]));
    asm("v_permlane32_swap_b32 %0, %1" : "+v"(pk[5]), "+v"(pk[7]));
    int4 f0 = make_int4(pk[0], pk[1], pk[2], pk[3]);  // s 0..15 of chunk
    int4 f1 = make_int4(pk[4], pk[5], pk[6], pk[7]);  // s 16..31
    hacc = mfma32(pun(f0), va, hacc);
    hacc = mfma32(pun(f1), vc, hacc);
    __syncthreads();
  }
  ushort* o = h1p + (size_t)spart * QN32_ + (size_t)b * T_ * 32;
#pragma unroll
  for (int r = 0; r < 16; ++r) {
    int trow = t0 + (r & 3) + 8 * (r >> 2) + 4 * hi;
    o[(size_t)trow * 32 + lo] = f2bf(hacc[r]);
  }
}

// ---------------------------------------------------------------------------
// K4: out[r][d] = sum_h h1[r][h] * wh[h][d]; folds 4 bf16 s-part partials.
// ---------------------------------------------------------------------------
__global__ __launch_bounds__(256) void out_kernel(const ushort* __restrict__ h1p,
                                                  const float* __restrict__ wh,
                                                  float* __restrict__ out) {
  __shared__ __align__(16) float s_h1[16 * 24];
  const int tid = threadIdx.x;
  const long rbase = (long)blockIdx.x * 16;
  if (tid < 48) {
    const int r = tid / 3, c8 = tid - 3 * r;  // cols [8c8, 8c8+8) < 24
    float s[8] = {0.f, 0.f, 0.f, 0.f, 0.f, 0.f, 0.f, 0.f};
#pragma unroll
    for (int part = 0; part < 4; ++part) {
      int4 v = *(const int4*)&h1p[(size_t)part * QN32_ +
                                  (size_t)(rbase + r) * 32 + c8 * 8];
      const ushort* u = (const ushort*)&v;
#pragma unroll
      for (int j = 0; j < 8; ++j) s[j] += bf2f(u[j]);
    }
#pragma unroll
    for (int j = 0; j < 8; ++j) s_h1[r * 24 + c8 * 8 + j] = s[j];
  }
  __syncthreads();
  for (int c = 0; c < 4; ++c) {
    const int dd = c * 256 + tid;
    float wr[24];
#pragma unroll
    for (int h = 0; h < 24; ++h) wr[h] = wh[h * D_ + dd];
#pragma unroll 1
    for (int r = 0; r < 16; ++r) {
      float a = 0.f;
#pragma unroll
      for (int j = 0; j < 6; ++j) {
        float4 hv = *(const float4*)(s_h1 + r * 24 + 4 * j);
        a = fmaf(hv.x, wr[4 * j], a);
        a = fmaf(hv.y, wr[4 * j + 1], a);
        a = fmaf(hv.z, wr[4 * j + 2], a);
        a = fmaf(hv.w, wr[4 * j + 3], a);
      }
      out[(rbase + r) * D_ + dd] = a;
    }
  }
}

// ---------------------------------------------------------------------------
extern "C" void kernel_launch(void* const* d_in, const int* in_sizes, int n_in,
                              void* d_out, int out_size, void* d_ws,
                              size_t ws_size, hipStream_t stream) {
  const float* encoded = (const float*)d_in[0];
  const float* text = (const float*)d_in[1];
  const float* wq = (const float*)d_in[2];
  const float* wk = (const float*)d_in[3];
  const float* wv = (const float*)d_in[4];
  const float* wh = (const float*)d_in[5];
  float* out = (float*)d_out;

  // workspace layout: ~17.7 MiB total
  ushort* qb = (ushort*)d_ws;               // [B][T][32] bf16  (2 MiB)
  ushort* kbuf = qb + QN32_;                // [B][S][32] bf16  (2 MiB)
  float* vv = (float*)(kbuf + QN32_);       // [B][S][24] f32   (3 MiB)
  float* dpart = vv + (size_t)BS_ * H_;     // [4][B*S] f32     (0.5 MiB)
  ushort* vsT = (ushort*)(dpart + 4 * BS_); // [B][32][S] bf16  (2 MiB)
  ushort* h1p = vsT + (size_t)B_ * 32 * S_; // [4][B][T][32] bf16 (8 MiB)
  ushort* wpk = h1p + 4 * QN32_;            // [3][128][24][8] bf16 (144 KiB)

  prep_w<<<36, 256, 0, stream>>>(wq, wk, wv, wpk);
  proj_unified<<<2048, 256, 0, stream>>>(text, encoded, wpk, qb, kbuf, vv);
  colsum_mfma<<<dim3(S_ / 128, B_, 4), 256, 0, stream>>>(qb, kbuf, dpart);
  vscale_kernel<<<(B_ * 32 * (S_ / 4)) / 256, 256, 0, stream>>>(vv, dpart, vsT);
  attn_mfma<<<dim3(T_ / 128, B_, 4), 256, 0, stream>>>(qb, kbuf, vsT, h1p);
  out_kernel<<<NROW_ / 16, 256, 0, stream>>>(h1p, wh, out);
}